// Round 8
// baseline (259.261 us; speedup 1.0000x reference)
//
#include <hip/hip_runtime.h>

#define N_HID 128
#define CAP   64          // bucket slots per node (Poisson(16) degree; overflow handled exactly)
#define OVF_CAP 8192
#define NSLICE 8

typedef short bf16x8 __attribute__((ext_vector_type(8)));
typedef float f32x4  __attribute__((ext_vector_type(4)));

// round-to-nearest-even f32 -> bf16 bits
static __device__ __forceinline__ unsigned short f2bf(float f)
{
    unsigned int u = __float_as_uint(f);
    u = (u + 0x7fffu + ((u >> 16) & 1u)) >> 16;
    return (unsigned short)u;
}
static __device__ __forceinline__ float bf2f(unsigned int bits16)
{
    return __uint_as_float(bits16 << 16);
}

// ---------------------------------------------------------------------------
// Fragmentize: f32 [rows,128] -> bf16 MFMA-fragment order.
// Frag layout per 16-row tile rt: [kc 0..3][lane 0..63][j 0..7] ushort,
// lane = ((k>>3)&3)*16 + (row&15), j = k&7 (A/B operand of mfma 16x16x32_bf16)
// ---------------------------------------------------------------------------
__global__ __launch_bounds__(256) void fragmentize(
    const float* __restrict__ h,
    const float* __restrict__ We,
    const float* __restrict__ Ws,
    unsigned short* __restrict__ Ah,
    unsigned short* __restrict__ Be,
    unsigned short* __restrict__ Bs,
    int n, int nrt)
{
    int b = blockIdx.x;
    const float* src; unsigned short* dstF; int rt, nrows;
    if (b < nrt)          { src = h;  dstF = Ah; rt = b;           nrows = n;   }
    else if (b < nrt + 8) { src = We; dstF = Be; rt = b - nrt;     nrows = 128; }
    else                  { src = Ws; dstF = Bs; rt = b - nrt - 8; nrows = 128; }

    int t  = threadIdx.x;
    int kc = t >> 6;          // 0..3 (k-chunk of 32)
    int l  = t & 63;          // lane slot
    int m  = l & 15;          // row within tile
    int q  = l >> 4;          // k-subchunk of 8

    int row = rt * 16 + m;
    if (row > nrows - 1) row = nrows - 1;

    const float* p = &src[(size_t)row * N_HID + kc * 32 + q * 8];
    float4 v0 = *(const float4*)p;
    float4 v1 = *(const float4*)(p + 4);

    uint4 pk;
    pk.x = (unsigned int)f2bf(v0.x) | ((unsigned int)f2bf(v0.y) << 16);
    pk.y = (unsigned int)f2bf(v0.z) | ((unsigned int)f2bf(v0.w) << 16);
    pk.z = (unsigned int)f2bf(v1.x) | ((unsigned int)f2bf(v1.y) << 16);
    pk.w = (unsigned int)f2bf(v1.z) | ((unsigned int)f2bf(v1.w) << 16);

    *(uint4*)&dstF[(size_t)rt * 2048 + kc * 512 + l * 8] = pk;
}

// ---------------------------------------------------------------------------
// Fused dual MFMA GEMM in ONE launch: blocks [0,nwb) do We->msg(bf16),
// blocks [nwb,2*nwb) do Ws->out(f32)+bias. One wave per 16-row tile.
// D layout: col = lane&15, row = (lane>>4)*4 + reg.
// ---------------------------------------------------------------------------
__global__ __launch_bounds__(256) void gemm_mfma2(
    const unsigned short* __restrict__ Afrag,
    const unsigned short* __restrict__ Be,
    const unsigned short* __restrict__ Bsf,
    const float* __restrict__ bias,
    unsigned short* __restrict__ msgOut,
    float* __restrict__ fOut,
    int n, int nrt, int nwb)
{
    int b    = blockIdx.x;
    bool sp  = b >= nwb;             // self pass?
    int bl   = sp ? b - nwb : b;
    int w    = bl * 4 + ((int)threadIdx.x >> 6);
    if (w >= nrt) return;
    int l = threadIdx.x & 63;

    const unsigned short* Bfrag = sp ? Bsf : Be;

    const bf16x8* Ap = (const bf16x8*)(Afrag + (size_t)w * 2048);
    bf16x8 a0 = Ap[l], a1 = Ap[64 + l], a2 = Ap[128 + l], a3 = Ap[192 + l];

    const int m0   = w * 16;
    const int colb = l & 15;
    const int rq   = (l >> 4) * 4;

#pragma unroll
    for (int ct = 0; ct < 8; ++ct) {
        const bf16x8* Bp = (const bf16x8*)(Bfrag + (size_t)ct * 2048);
        f32x4 acc = {0.f, 0.f, 0.f, 0.f};
        acc = __builtin_amdgcn_mfma_f32_16x16x32_bf16(a0, Bp[l],       acc, 0, 0, 0);
        acc = __builtin_amdgcn_mfma_f32_16x16x32_bf16(a1, Bp[64 + l],  acc, 0, 0, 0);
        acc = __builtin_amdgcn_mfma_f32_16x16x32_bf16(a2, Bp[128 + l], acc, 0, 0, 0);
        acc = __builtin_amdgcn_mfma_f32_16x16x32_bf16(a3, Bp[192 + l], acc, 0, 0, 0);

        int col = ct * 16 + colb;
        if (sp) {
            float bv = bias[col];
#pragma unroll
            for (int r = 0; r < 4; ++r) {
                int row = m0 + rq + r;
                if (row < n) fOut[(size_t)row * N_HID + col] = acc[r] + bv;
            }
        } else {
#pragma unroll
            for (int r = 0; r < 4; ++r) {
                int row = m0 + rq + r;
                if (row < n) msgOut[(size_t)row * N_HID + col] = f2bf(acc[r]);
            }
        }
    }
}

// ---------------------------------------------------------------------------
// Phase 1a: per-slice edge counts (slice = 8*d/n).
// ---------------------------------------------------------------------------
__global__ __launch_bounds__(256) void part_count(
    const int* __restrict__ dst, int* __restrict__ scnt, int E, int n)
{
    __shared__ int loc[NSLICE];
    if (threadIdx.x < NSLICE) loc[threadIdx.x] = 0;
    __syncthreads();
    int i = blockIdx.x * 256 + threadIdx.x;
    if (i < E) {
        int sl = (int)(((long long)dst[i] * NSLICE) / n);
        atomicAdd(&loc[sl], 1);
    }
    __syncthreads();
    if (threadIdx.x < NSLICE) atomicAdd(&scnt[threadIdx.x], loc[threadIdx.x]);
}

// ---------------------------------------------------------------------------
// Phase 1b: 8-entry exclusive scan -> sbase[9], cursor copy.
// ---------------------------------------------------------------------------
__global__ void scan8(const int* __restrict__ scnt,
                      int* __restrict__ sbase, int* __restrict__ scur)
{
    if (threadIdx.x == 0) {
        int s = 0;
        for (int i = 0; i < NSLICE; ++i) { sbase[i] = s; scur[i] = s; s += scnt[i]; }
        sbase[NSLICE] = s;
    }
}

// ---------------------------------------------------------------------------
// Phase 1c: partition edges into dense per-slice queues, packed u32
// (d<<16)|s — requires n <= 65536 (n=50000 here). Block-contiguous writes.
// ---------------------------------------------------------------------------
__global__ __launch_bounds__(256) void part_scatter(
    const int* __restrict__ src, const int* __restrict__ dst,
    int* __restrict__ scur, unsigned int* __restrict__ part, int E, int n)
{
    __shared__ int loc[NSLICE];
    __shared__ int base[NSLICE];
    if (threadIdx.x < NSLICE) loc[threadIdx.x] = 0;
    __syncthreads();
    int i = blockIdx.x * 256 + threadIdx.x;
    int d = 0, s = 0, sl = 0, off = 0;
    bool ok = i < E;
    if (ok) {
        d = dst[i]; s = src[i];
        sl  = (int)(((long long)d * NSLICE) / n);
        off = atomicAdd(&loc[sl], 1);
    }
    __syncthreads();
    if (threadIdx.x < NSLICE)
        base[threadIdx.x] = atomicAdd(&scur[threadIdx.x], loc[threadIdx.x]);
    __syncthreads();
    if (ok)
        part[base[sl] + off] = ((unsigned int)d << 16) | (unsigned int)s;
}

// ---------------------------------------------------------------------------
// Phase 2: bucket scatter over DENSE per-slice lists. slice = blockIdx&7
// (XCD-affine under round-robin dispatch) -> cnt/bucket lines written from
// ~one XCD; zero read amplification; all lanes active.
// ---------------------------------------------------------------------------
__global__ __launch_bounds__(256) void bucket_scatter2(
    const unsigned int* __restrict__ part,
    const int* __restrict__ sbase,
    int* __restrict__ cnt,
    int* __restrict__ bucket,
    int* __restrict__ ovfn,
    long long* __restrict__ ovf)
{
    const int slice = blockIdx.x & 7;
    const int g     = blockIdx.x >> 3;
    const int nG    = (int)(gridDim.x >> 3);
    const int lo    = sbase[slice];
    const int hi    = sbase[slice + 1];
    const int m     = hi - lo;

    const int chunk = (m + nG - 1) / nG;
    const int e0 = lo + g * chunk;
    int e1 = e0 + chunk; if (e1 > hi) e1 = hi;

    for (int e = e0 + (int)threadIdx.x; e < e1; e += 256) {
        unsigned int pk = part[e];
        int d = (int)(pk >> 16);
        int s = (int)(pk & 0xffffu);
        int c = atomicAdd(&cnt[d], 1);
        if (c < CAP) {
            bucket[(size_t)d * CAP + c] = s;
        } else {
            int o = atomicAdd(ovfn, 1);
            if (o < OVF_CAP) ovf[o] = ((long long)d << 32) | (unsigned int)s;
        }
    }
}

// ---------------------------------------------------------------------------
// Per-node gather(bf16 msg) + mean + self(f32, already in out) + relu.
// One wave per node; lane reads one uint = 2 bf16 (256B/row coalesced).
// ---------------------------------------------------------------------------
__global__ __launch_bounds__(256) void gather_finish(
    const int* __restrict__ cnt,
    const int* __restrict__ bucket,
    const int* __restrict__ ovfn,
    const long long* __restrict__ ovf,
    const unsigned short* __restrict__ msg,
    float* __restrict__ out,
    int n)
{
    int node = blockIdx.x * 4 + (threadIdx.x >> 6);
    if (node >= n) return;
    int lane = threadIdx.x & 63;
    int deg  = cnt[node];
    int m    = deg < CAP ? deg : CAP;

    const int* bk = &bucket[(size_t)node * CAP];
    const unsigned int* m32 = (const unsigned int*)msg;   // 64 uints per row

    float ax = 0.f, ay = 0.f;
    int i = 0;
    for (; i + 4 <= m; i += 4) {
        int s0 = bk[i + 0], s1 = bk[i + 1], s2 = bk[i + 2], s3 = bk[i + 3];
        unsigned int v0 = m32[(size_t)s0 * 64 + lane];
        unsigned int v1 = m32[(size_t)s1 * 64 + lane];
        unsigned int v2 = m32[(size_t)s2 * 64 + lane];
        unsigned int v3 = m32[(size_t)s3 * 64 + lane];
        ax += bf2f(v0 & 0xffffu) + bf2f(v1 & 0xffffu) + bf2f(v2 & 0xffffu) + bf2f(v3 & 0xffffu);
        ay += bf2f(v0 >> 16)     + bf2f(v1 >> 16)     + bf2f(v2 >> 16)     + bf2f(v3 >> 16);
    }
    for (; i < m; ++i) {
        unsigned int v = m32[(size_t)bk[i] * 64 + lane];
        ax += bf2f(v & 0xffffu);
        ay += bf2f(v >> 16);
    }

    if (deg > CAP) {                 // exact fallback; never taken on this data
        int no = *ovfn; if (no > OVF_CAP) no = OVF_CAP;
        for (int o = 0; o < no; ++o) {
            long long pk = ovf[o];
            if ((int)(pk >> 32) == node) {
                unsigned int v = m32[(size_t)(unsigned int)pk * 64 + lane];
                ax += bf2f(v & 0xffffu);
                ay += bf2f(v >> 16);
            }
        }
    }

    float sc = deg > 0 ? 1.0f / (float)deg : 0.f;

    float2* o2 = (float2*)out;
    float2 sv  = o2[(size_t)node * 64 + lane];
    float2 r;
    r.x = fmaxf(sv.x + ax * sc, 0.f);
    r.y = fmaxf(sv.y + ay * sc, 0.f);
    o2[(size_t)node * 64 + lane] = r;
}

// ---------------------------------------------------------------------------
extern "C" void kernel_launch(void* const* d_in, const int* in_sizes, int n_in,
                              void* d_out, int out_size, void* d_ws, size_t ws_size,
                              hipStream_t stream)
{
    const float* h   = (const float*)d_in[0];
    const int*   src = (const int*)d_in[1];
    const int*   dst = (const int*)d_in[2];
    const float* We  = (const float*)d_in[3];
    const float* Ws  = (const float*)d_in[4];
    const float* bs  = (const float*)d_in[5];
    float*       out = (float*)d_out;

    const int n   = in_sizes[0] / N_HID;    // 50000
    const int E   = in_sizes[1];            // 800000
    const int nrt = (n + 15) / 16;          // 3125 row tiles
    const int nwb = (nrt + 3) / 4;          // wave-blocks per gemm pass

    // workspace (~29.5 MB). bucket ALIASES Ah — stream order:
    // fragmentize -> gemm (last reader of Ah) -> bucket_scatter2 (writer) -> gather.
    unsigned short* msg = (unsigned short*)d_ws;              // n*128 bf16      (12.8 MB)
    unsigned short* Ah  = msg + (size_t)n * N_HID;            // nrt*2048 ushort (12.8 MB)
    int*            bucket = (int*)Ah;                        // n*CAP int       (same 12.8 MB)
    unsigned short* Be  = Ah + (size_t)nrt * 2048;            // 8*2048
    unsigned short* Bs  = Be + 8 * 2048;                      // 8*2048
    int*  cnt  = (int*)(Bs + 8 * 2048);                       // n
    int*  ovfn = cnt + n;                                     // 1 (+pad)
    long long* ovf = (long long*)(ovfn + 8);                  // OVF_CAP
    int*  scnt  = (int*)(ovf + OVF_CAP);                      // 8
    int*  sbase = scnt + 8;                                   // 9 (+pad)
    int*  scur  = sbase + 16;                                 // 8
    unsigned int* part = (unsigned int*)(scur + 8);           // E u32 (3.2 MB)

    hipMemsetAsync(cnt, 0, sizeof(int) * (size_t)(n + 8), stream);
    hipMemsetAsync(scnt, 0, sizeof(int) * 8, stream);

    part_count<<<(E + 255) / 256, 256, 0, stream>>>(dst, scnt, E, n);
    scan8<<<1, 64, 0, stream>>>(scnt, sbase, scur);
    part_scatter<<<(E + 255) / 256, 256, 0, stream>>>(src, dst, scur, part, E, n);

    fragmentize<<<nrt + 16, 256, 0, stream>>>(h, We, Ws, Ah, Be, Bs, n, nrt);
    gemm_mfma2<<<2 * nwb, 256, 0, stream>>>(Ah, Be, Bs, bs, msg, out, n, nrt, nwb);

    bucket_scatter2<<<512, 256, 0, stream>>>(part, sbase, cnt, bucket, ovfn, ovf);
    gather_finish<<<(n + 3) / 4, 256, 0, stream>>>(cnt, bucket, ovfn, ovf, msg, out, n);
}

// Round 9
// 196.167 us; speedup vs baseline: 1.3216x; 1.3216x over previous
//
#include <hip/hip_runtime.h>

#define N_HID 128
#define CAP   64          // bucket slots per node (Poisson(16) degree; overflow handled exactly)
#define OVF_CAP 8192
#define NSLICE 8
#define PBLK   256        // partition grid size (fixed: scan kernel scans PBLK*NSLICE counts)

typedef short bf16x8 __attribute__((ext_vector_type(8)));
typedef float f32x4  __attribute__((ext_vector_type(4)));

// round-to-nearest-even f32 -> bf16 bits
static __device__ __forceinline__ unsigned short f2bf(float f)
{
    unsigned int u = __float_as_uint(f);
    u = (u + 0x7fffu + ((u >> 16) & 1u)) >> 16;
    return (unsigned short)u;
}
static __device__ __forceinline__ float bf2f(unsigned int bits16)
{
    return __uint_as_float(bits16 << 16);
}

// ---------------------------------------------------------------------------
// Fragmentize: f32 [rows,128] -> bf16 MFMA-fragment order.
// Frag layout per 16-row tile rt: [kc 0..3][lane 0..63][j 0..7] ushort,
// lane = ((k>>3)&3)*16 + (row&15), j = k&7 (A/B operand of mfma 16x16x32_bf16)
// ---------------------------------------------------------------------------
__global__ __launch_bounds__(256) void fragmentize(
    const float* __restrict__ h,
    const float* __restrict__ We,
    const float* __restrict__ Ws,
    unsigned short* __restrict__ Ah,
    unsigned short* __restrict__ Be,
    unsigned short* __restrict__ Bs,
    int n, int nrt)
{
    int b = blockIdx.x;
    const float* src; unsigned short* dstF; int rt, nrows;
    if (b < nrt)          { src = h;  dstF = Ah; rt = b;           nrows = n;   }
    else if (b < nrt + 8) { src = We; dstF = Be; rt = b - nrt;     nrows = 128; }
    else                  { src = Ws; dstF = Bs; rt = b - nrt - 8; nrows = 128; }

    int t  = threadIdx.x;
    int kc = t >> 6;          // 0..3 (k-chunk of 32)
    int l  = t & 63;          // lane slot
    int m  = l & 15;          // row within tile
    int q  = l >> 4;          // k-subchunk of 8

    int row = rt * 16 + m;
    if (row > nrows - 1) row = nrows - 1;

    const float* p = &src[(size_t)row * N_HID + kc * 32 + q * 8];
    float4 v0 = *(const float4*)p;
    float4 v1 = *(const float4*)(p + 4);

    uint4 pk;
    pk.x = (unsigned int)f2bf(v0.x) | ((unsigned int)f2bf(v0.y) << 16);
    pk.y = (unsigned int)f2bf(v0.z) | ((unsigned int)f2bf(v0.w) << 16);
    pk.z = (unsigned int)f2bf(v1.x) | ((unsigned int)f2bf(v1.y) << 16);
    pk.w = (unsigned int)f2bf(v1.z) | ((unsigned int)f2bf(v1.w) << 16);

    *(uint4*)&dstF[(size_t)rt * 2048 + kc * 512 + l * 8] = pk;
}

// ---------------------------------------------------------------------------
// Fused dual MFMA GEMM in ONE launch: blocks [0,nwb) do We->msg(bf16),
// blocks [nwb,2*nwb) do Ws->out(f32)+bias. One wave per 16-row tile.
// D layout: col = lane&15, row = (lane>>4)*4 + reg.
// ---------------------------------------------------------------------------
__global__ __launch_bounds__(256) void gemm_mfma2(
    const unsigned short* __restrict__ Afrag,
    const unsigned short* __restrict__ Be,
    const unsigned short* __restrict__ Bsf,
    const float* __restrict__ bias,
    unsigned short* __restrict__ msgOut,
    float* __restrict__ fOut,
    int n, int nrt, int nwb)
{
    int b    = blockIdx.x;
    bool sp  = b >= nwb;             // self pass?
    int bl   = sp ? b - nwb : b;
    int w    = bl * 4 + ((int)threadIdx.x >> 6);
    if (w >= nrt) return;
    int l = threadIdx.x & 63;

    const unsigned short* Bfrag = sp ? Bsf : Be;

    const bf16x8* Ap = (const bf16x8*)(Afrag + (size_t)w * 2048);
    bf16x8 a0 = Ap[l], a1 = Ap[64 + l], a2 = Ap[128 + l], a3 = Ap[192 + l];

    const int m0   = w * 16;
    const int colb = l & 15;
    const int rq   = (l >> 4) * 4;

#pragma unroll
    for (int ct = 0; ct < 8; ++ct) {
        const bf16x8* Bp = (const bf16x8*)(Bfrag + (size_t)ct * 2048);
        f32x4 acc = {0.f, 0.f, 0.f, 0.f};
        acc = __builtin_amdgcn_mfma_f32_16x16x32_bf16(a0, Bp[l],       acc, 0, 0, 0);
        acc = __builtin_amdgcn_mfma_f32_16x16x32_bf16(a1, Bp[64 + l],  acc, 0, 0, 0);
        acc = __builtin_amdgcn_mfma_f32_16x16x32_bf16(a2, Bp[128 + l], acc, 0, 0, 0);
        acc = __builtin_amdgcn_mfma_f32_16x16x32_bf16(a3, Bp[192 + l], acc, 0, 0, 0);

        int col = ct * 16 + colb;
        if (sp) {
            float bv = bias[col];
#pragma unroll
            for (int r = 0; r < 4; ++r) {
                int row = m0 + rq + r;
                if (row < n) fOut[(size_t)row * N_HID + col] = acc[r] + bv;
            }
        } else {
#pragma unroll
            for (int r = 0; r < 4; ++r) {
                int row = m0 + rq + r;
                if (row < n) msgOut[(size_t)row * N_HID + col] = f2bf(acc[r]);
            }
        }
    }
}

// ---------------------------------------------------------------------------
// Partition 1: per-block per-slice counts, NO atomics. Per-thread register
// counters (8 compare-adds/edge), shuffle+LDS block reduce, plain stores to
// blockCnt[sl*PBLK + b].
// ---------------------------------------------------------------------------
__global__ __launch_bounds__(256) void part_count(
    const int* __restrict__ dst, int* __restrict__ blockCnt, int E, int n)
{
    int t = threadIdx.x, b = blockIdx.x;
    int c[NSLICE];
#pragma unroll
    for (int s = 0; s < NSLICE; ++s) c[s] = 0;

    for (int e = b * 256 + t; e < E; e += PBLK * 256) {
        int sl = (int)(((long long)dst[e] * NSLICE) / n);
#pragma unroll
        for (int s = 0; s < NSLICE; ++s) c[s] += (sl == s);
    }

    __shared__ int red[NSLICE * 4];
    int lane = t & 63, wid = t >> 6;
#pragma unroll
    for (int s = 0; s < NSLICE; ++s) {
        int v = c[s];
#pragma unroll
        for (int off = 32; off; off >>= 1) v += __shfl_down(v, off);
        if (lane == 0) red[s * 4 + wid] = v;
    }
    __syncthreads();
    if (t < NSLICE)
        blockCnt[t * PBLK + b] = red[t*4+0] + red[t*4+1] + red[t*4+2] + red[t*4+3];
}

// ---------------------------------------------------------------------------
// Partition 2: exclusive scan of PBLK*NSLICE=2048 counts (one block, thread
// handles 8 consecutive) -> blockBase (same layout) + sbase[9].
// ---------------------------------------------------------------------------
__global__ __launch_bounds__(256) void part_scan(
    const int* __restrict__ blockCnt, int* __restrict__ blockBase,
    int* __restrict__ sbase, int E)
{
    __shared__ int ws[4];
    int t = threadIdx.x, lane = t & 63, wid = t >> 6;
    int v[8]; int s = 0;
#pragma unroll
    for (int i = 0; i < 8; ++i) { v[i] = blockCnt[t * 8 + i]; s += v[i]; }
    int val = s;
#pragma unroll
    for (int off = 1; off < 64; off <<= 1) {
        int y = __shfl_up(val, off);
        if (lane >= off) val += y;
    }
    if (lane == 63) ws[wid] = val;
    __syncthreads();
    if (t == 0) { int a = 0; for (int w = 0; w < 4; ++w) { int tmp = ws[w]; ws[w] = a; a += tmp; } }
    __syncthreads();
    int excl = ws[wid] + val - s;
#pragma unroll
    for (int i = 0; i < 8; ++i) { int tv = v[i]; blockBase[t * 8 + i] = excl; excl += tv; }
    __syncthreads();
    if (t < NSLICE) sbase[t] = blockBase[t * PBLK];
    if (t == 0)     sbase[NSLICE] = E;
}

// ---------------------------------------------------------------------------
// Partition 3: scatter edges into dense per-slice queues using precomputed
// per-(block,slice) bases — only LDS atomics. Packed u32 (d<<16)|s (n<=65536).
// ---------------------------------------------------------------------------
__global__ __launch_bounds__(256) void part_scatter(
    const int* __restrict__ src, const int* __restrict__ dst,
    const int* __restrict__ blockBase, unsigned int* __restrict__ part,
    int E, int n)
{
    __shared__ int cur[NSLICE];
    int t = threadIdx.x, b = blockIdx.x;
    if (t < NSLICE) cur[t] = blockBase[t * PBLK + b];
    __syncthreads();
    for (int e = b * 256 + t; e < E; e += PBLK * 256) {
        int d = dst[e], s = src[e];
        int sl  = (int)(((long long)d * NSLICE) / n);
        int pos = atomicAdd(&cur[sl], 1);
        part[pos] = ((unsigned int)d << 16) | (unsigned int)s;
    }
}

// ---------------------------------------------------------------------------
// Bucket scatter over DENSE per-slice lists. slice = blockIdx&7 (XCD-affine
// under round-robin dispatch) -> cnt/bucket lines written from ~one XCD;
// zero read amplification; all lanes active.
// ---------------------------------------------------------------------------
__global__ __launch_bounds__(256) void bucket_scatter2(
    const unsigned int* __restrict__ part,
    const int* __restrict__ sbase,
    int* __restrict__ cnt,
    int* __restrict__ bucket,
    int* __restrict__ ovfn,
    long long* __restrict__ ovf)
{
    const int slice = blockIdx.x & 7;
    const int g     = blockIdx.x >> 3;
    const int nG    = (int)(gridDim.x >> 3);
    const int lo    = sbase[slice];
    const int hi    = sbase[slice + 1];
    const int m     = hi - lo;

    const int chunk = (m + nG - 1) / nG;
    const int e0 = lo + g * chunk;
    int e1 = e0 + chunk; if (e1 > hi) e1 = hi;

    for (int e = e0 + (int)threadIdx.x; e < e1; e += 256) {
        unsigned int pk = part[e];
        int d = (int)(pk >> 16);
        int s = (int)(pk & 0xffffu);
        int c = atomicAdd(&cnt[d], 1);
        if (c < CAP) {
            bucket[(size_t)d * CAP + c] = s;
        } else {
            int o = atomicAdd(ovfn, 1);
            if (o < OVF_CAP) ovf[o] = ((long long)d << 32) | (unsigned int)s;
        }
    }
}

// ---------------------------------------------------------------------------
// Per-node gather(bf16 msg) + mean + self(f32, already in out) + relu.
// One wave per node; lane reads one uint = 2 bf16 (256B/row coalesced).
// ---------------------------------------------------------------------------
__global__ __launch_bounds__(256) void gather_finish(
    const int* __restrict__ cnt,
    const int* __restrict__ bucket,
    const int* __restrict__ ovfn,
    const long long* __restrict__ ovf,
    const unsigned short* __restrict__ msg,
    float* __restrict__ out,
    int n)
{
    int node = blockIdx.x * 4 + (threadIdx.x >> 6);
    if (node >= n) return;
    int lane = threadIdx.x & 63;
    int deg  = cnt[node];
    int m    = deg < CAP ? deg : CAP;

    const int* bk = &bucket[(size_t)node * CAP];
    const unsigned int* m32 = (const unsigned int*)msg;   // 64 uints per row

    float ax = 0.f, ay = 0.f;
    int i = 0;
    for (; i + 4 <= m; i += 4) {
        int s0 = bk[i + 0], s1 = bk[i + 1], s2 = bk[i + 2], s3 = bk[i + 3];
        unsigned int v0 = m32[(size_t)s0 * 64 + lane];
        unsigned int v1 = m32[(size_t)s1 * 64 + lane];
        unsigned int v2 = m32[(size_t)s2 * 64 + lane];
        unsigned int v3 = m32[(size_t)s3 * 64 + lane];
        ax += bf2f(v0 & 0xffffu) + bf2f(v1 & 0xffffu) + bf2f(v2 & 0xffffu) + bf2f(v3 & 0xffffu);
        ay += bf2f(v0 >> 16)     + bf2f(v1 >> 16)     + bf2f(v2 >> 16)     + bf2f(v3 >> 16);
    }
    for (; i < m; ++i) {
        unsigned int v = m32[(size_t)bk[i] * 64 + lane];
        ax += bf2f(v & 0xffffu);
        ay += bf2f(v >> 16);
    }

    if (deg > CAP) {                 // exact fallback; never taken on this data
        int no = *ovfn; if (no > OVF_CAP) no = OVF_CAP;
        for (int o = 0; o < no; ++o) {
            long long pk = ovf[o];
            if ((int)(pk >> 32) == node) {
                unsigned int v = m32[(size_t)(unsigned int)pk * 64 + lane];
                ax += bf2f(v & 0xffffu);
                ay += bf2f(v >> 16);
            }
        }
    }

    float sc = deg > 0 ? 1.0f / (float)deg : 0.f;

    float2* o2 = (float2*)out;
    float2 sv  = o2[(size_t)node * 64 + lane];
    float2 r;
    r.x = fmaxf(sv.x + ax * sc, 0.f);
    r.y = fmaxf(sv.y + ay * sc, 0.f);
    o2[(size_t)node * 64 + lane] = r;
}

// ---------------------------------------------------------------------------
extern "C" void kernel_launch(void* const* d_in, const int* in_sizes, int n_in,
                              void* d_out, int out_size, void* d_ws, size_t ws_size,
                              hipStream_t stream)
{
    const float* h   = (const float*)d_in[0];
    const int*   src = (const int*)d_in[1];
    const int*   dst = (const int*)d_in[2];
    const float* We  = (const float*)d_in[3];
    const float* Ws  = (const float*)d_in[4];
    const float* bs  = (const float*)d_in[5];
    float*       out = (float*)d_out;

    const int n   = in_sizes[0] / N_HID;    // 50000
    const int E   = in_sizes[1];            // 800000
    const int nrt = (n + 15) / 16;          // 3125 row tiles
    const int nwb = (nrt + 3) / 4;          // wave-blocks per gemm pass

    // workspace (~29.5 MB). bucket ALIASES Ah — stream order:
    // fragmentize -> gemm (last reader of Ah) -> bucket_scatter2 (writer) -> gather.
    unsigned short* msg = (unsigned short*)d_ws;              // n*128 bf16      (12.8 MB)
    unsigned short* Ah  = msg + (size_t)n * N_HID;            // nrt*2048 ushort (12.8 MB)
    int*            bucket = (int*)Ah;                        // n*CAP int       (same 12.8 MB)
    unsigned short* Be  = Ah + (size_t)nrt * 2048;            // 8*2048
    unsigned short* Bs  = Be + 8 * 2048;                      // 8*2048
    int*  cnt  = (int*)(Bs + 8 * 2048);                       // n
    int*  ovfn = cnt + n;                                     // 1 (+pad)
    long long* ovf = (long long*)(ovfn + 8);                  // OVF_CAP
    int*  blockCnt  = (int*)(ovf + OVF_CAP);                  // PBLK*NSLICE
    int*  blockBase = blockCnt + PBLK * NSLICE;               // PBLK*NSLICE
    int*  sbase     = blockBase + PBLK * NSLICE;              // 9 (+pad)
    unsigned int* part = (unsigned int*)(sbase + 16);         // E u32 (3.2 MB)

    hipMemsetAsync(cnt, 0, sizeof(int) * (size_t)(n + 8), stream);

    part_count<<<PBLK, 256, 0, stream>>>(dst, blockCnt, E, n);
    part_scan<<<1, 256, 0, stream>>>(blockCnt, blockBase, sbase, E);
    part_scatter<<<PBLK, 256, 0, stream>>>(src, dst, blockBase, part, E, n);

    fragmentize<<<nrt + 16, 256, 0, stream>>>(h, We, Ws, Ah, Be, Bs, n, nrt);
    gemm_mfma2<<<2 * nwb, 256, 0, stream>>>(Ah, Be, Bs, bs, msg, out, n, nrt, nwb);

    bucket_scatter2<<<512, 256, 0, stream>>>(part, sbase, cnt, bucket, ovfn, ovf);
    gather_finish<<<(n + 3) / 4, 256, 0, stream>>>(cnt, bucket, ovfn, ovf, msg, out, n);
}

// Round 10
// 192.982 us; speedup vs baseline: 1.3434x; 1.0165x over previous
//
#include <hip/hip_runtime.h>

#define N_HID 128
#define CAP   64          // bucket slots per node (Poisson(16) degree; overflow handled exactly)
#define OVF_CAP 8192
#define NSLICE 8
#define PBLK   256        // partition grid size (scan kernel scans PBLK*NSLICE counts)
#define LDW   132         // 128 + 4 pad words (breaks frag-read bank conflicts)

typedef short bf16x8 __attribute__((ext_vector_type(8)));
typedef float f32x4  __attribute__((ext_vector_type(4)));

// round-to-nearest-even f32 -> bf16 bits
static __device__ __forceinline__ unsigned short f2bf(float f)
{
    unsigned int u = __float_as_uint(f);
    u = (u + 0x7fffu + ((u >> 16) & 1u)) >> 16;
    return (unsigned short)u;
}
static __device__ __forceinline__ unsigned int pack2(float a, float b)
{
    return (unsigned int)f2bf(a) | ((unsigned int)f2bf(b) << 16);
}
static __device__ __forceinline__ float bf2f(unsigned int bits16)
{
    return __uint_as_float(bits16 << 16);
}

// ---------------------------------------------------------------------------
// Partition 1: per-block per-slice counts, NO atomics; also zeroes cnt/ovfn.
// ---------------------------------------------------------------------------
__global__ __launch_bounds__(256) void part_count(
    const int* __restrict__ dst, int* __restrict__ blockCnt,
    int* __restrict__ cnt, int* __restrict__ ovfn, int E, int n)
{
    int t = threadIdx.x, b = blockIdx.x;

    // fold in the zeroing of cnt[n] and ovfn (saves a memset dispatch)
    for (int i = b * 256 + t; i < n; i += PBLK * 256) cnt[i] = 0;
    if (b == 0 && t == 0) *ovfn = 0;

    int c[NSLICE];
#pragma unroll
    for (int s = 0; s < NSLICE; ++s) c[s] = 0;

    for (int e = b * 256 + t; e < E; e += PBLK * 256) {
        int sl = (int)(((long long)dst[e] * NSLICE) / n);
#pragma unroll
        for (int s = 0; s < NSLICE; ++s) c[s] += (sl == s);
    }

    __shared__ int red[NSLICE * 4];
    int lane = t & 63, wid = t >> 6;
#pragma unroll
    for (int s = 0; s < NSLICE; ++s) {
        int v = c[s];
#pragma unroll
        for (int off = 32; off; off >>= 1) v += __shfl_down(v, off);
        if (lane == 0) red[s * 4 + wid] = v;
    }
    __syncthreads();
    if (t < NSLICE)
        blockCnt[t * PBLK + b] = red[t*4+0] + red[t*4+1] + red[t*4+2] + red[t*4+3];
}

// ---------------------------------------------------------------------------
// Merged kernel: block 0 = exclusive scan of PBLK*NSLICE counts -> blockBase
// + sbase[9]; blocks 1..16 = weight fragmentize (We blocks 1-8, Ws 9-16).
// Frag layout per 16-row tile rt: [kc 0..3][lane 0..63][j 0..7] ushort,
// lane = ((k>>3)&3)*16 + (row&15), j = k&7.
// ---------------------------------------------------------------------------
__global__ __launch_bounds__(256) void scan_fragw(
    const int* __restrict__ blockCnt, int* __restrict__ blockBase,
    int* __restrict__ sbase, int E,
    const float* __restrict__ We, const float* __restrict__ Ws,
    unsigned short* __restrict__ Be, unsigned short* __restrict__ Bs)
{
    int t = threadIdx.x, b = blockIdx.x;
    if (b == 0) {
        __shared__ int wsm[4];
        int lane = t & 63, wid = t >> 6;
        int v[8]; int s = 0;
#pragma unroll
        for (int i = 0; i < 8; ++i) { v[i] = blockCnt[t * 8 + i]; s += v[i]; }
        int val = s;
#pragma unroll
        for (int off = 1; off < 64; off <<= 1) {
            int y = __shfl_up(val, off);
            if (lane >= off) val += y;
        }
        if (lane == 63) wsm[wid] = val;
        __syncthreads();
        if (t == 0) { int a = 0; for (int w = 0; w < 4; ++w) { int tmp = wsm[w]; wsm[w] = a; a += tmp; } }
        __syncthreads();
        int excl = wsm[wid] + val - s;
#pragma unroll
        for (int i = 0; i < 8; ++i) { int tv = v[i]; blockBase[t * 8 + i] = excl; excl += tv; }
        __syncthreads();
        if (t < NSLICE) sbase[t] = blockBase[t * PBLK];
        if (t == 0)     sbase[NSLICE] = E;
    } else {
        int bb = b - 1;
        const float* src = (bb < 8) ? We : Ws;
        unsigned short* dstF = (bb < 8) ? Be : Bs;
        int rt = bb & 7;

        int kc = t >> 6, l = t & 63, m = l & 15, q = l >> 4;
        const float* p = &src[(size_t)(rt * 16 + m) * N_HID + kc * 32 + q * 8];
        float4 v0 = *(const float4*)p;
        float4 v1 = *(const float4*)(p + 4);
        uint4 pk;
        pk.x = pack2(v0.x, v0.y);
        pk.y = pack2(v0.z, v0.w);
        pk.z = pack2(v1.x, v1.y);
        pk.w = pack2(v1.z, v1.w);
        *(uint4*)&dstF[(size_t)rt * 2048 + kc * 512 + l * 8] = pk;
    }
}

// ---------------------------------------------------------------------------
// Partition 3: scatter edges into dense per-slice queues using precomputed
// per-(block,slice) bases — only LDS atomics. Packed u32 (d<<16)|s (n<=65536).
// ---------------------------------------------------------------------------
__global__ __launch_bounds__(256) void part_scatter(
    const int* __restrict__ src, const int* __restrict__ dst,
    const int* __restrict__ blockBase, unsigned int* __restrict__ part,
    int E, int n)
{
    __shared__ int cur[NSLICE];
    int t = threadIdx.x, b = blockIdx.x;
    if (t < NSLICE) cur[t] = blockBase[t * PBLK + b];
    __syncthreads();
    for (int e = b * 256 + t; e < E; e += PBLK * 256) {
        int d = dst[e], s = src[e];
        int sl  = (int)(((long long)d * NSLICE) / n);
        int pos = atomicAdd(&cur[sl], 1);
        part[pos] = ((unsigned int)d << 16) | (unsigned int)s;
    }
}

// ---------------------------------------------------------------------------
// Fused dual GEMM with in-kernel A-fragmentization (no Ah round-trip).
// 4 waves/block, one 16-row tile per wave. Stage 16x128 f32 tile coalesced
// into padded LDS, convert to A-frags in registers ONCE, then run both
// B-passes: We -> msg (bf16), Ws -> out (f32 + bias).
// D layout: col = lane&15, row = (lane>>4)*4 + reg.
// ---------------------------------------------------------------------------
__global__ __launch_bounds__(256) void gemm_fused(
    const float* __restrict__ h,
    const unsigned short* __restrict__ Be,
    const unsigned short* __restrict__ Bsf,
    const float* __restrict__ bias,
    unsigned short* __restrict__ msgOut,
    float* __restrict__ fOut,
    int n, int nrt)
{
    __shared__ float As[4][16 * LDW];   // 33 KB, per-wave private slabs

    int t = threadIdx.x;
    int w = t >> 6, l = t & 63;
    int rt = blockIdx.x * 4 + w;
    bool active = rt < nrt;
    int rtc = active ? rt : nrt - 1;
    int row0 = rtc * 16;

    float* A = As[w];
    // stage 16 rows x 128 f32, fully coalesced float4
#pragma unroll
    for (int it = 0; it < 8; ++it) {
        int f  = it * 64 + l;
        int r  = f >> 5;
        int c4 = (f & 31) * 4;
        int gr = row0 + r; if (gr > n - 1) gr = n - 1;
        *(float4*)&A[r * LDW + c4] = *(const float4*)&h[(size_t)gr * N_HID + c4];
    }
    __syncthreads();   // all waves staged (uniform: no early returns)

    // build A-frags: lane l = q*16+m reads A[m][kc*32+q*8 .. +8]
    int m = l & 15, q = l >> 4;
    union { uint4 u; bf16x8 v; } af[4];
#pragma unroll
    for (int kc = 0; kc < 4; ++kc) {
        const float* p = &A[m * LDW + kc * 32 + q * 8];
        float4 v0 = *(const float4*)p;
        float4 v1 = *(const float4*)(p + 4);
        af[kc].u.x = pack2(v0.x, v0.y);
        af[kc].u.y = pack2(v0.z, v0.w);
        af[kc].u.z = pack2(v1.x, v1.y);
        af[kc].u.w = pack2(v1.z, v1.w);
    }

    const int colb = l & 15;
    const int rq   = (l >> 4) * 4;

#pragma unroll 1
    for (int pass = 0; pass < 2; ++pass) {
        const unsigned short* Bfrag = pass ? Bsf : Be;
#pragma unroll
        for (int ct = 0; ct < 8; ++ct) {
            const bf16x8* Bp = (const bf16x8*)(Bfrag + (size_t)ct * 2048);
            f32x4 acc = {0.f, 0.f, 0.f, 0.f};
            acc = __builtin_amdgcn_mfma_f32_16x16x32_bf16(af[0].v, Bp[l],       acc, 0, 0, 0);
            acc = __builtin_amdgcn_mfma_f32_16x16x32_bf16(af[1].v, Bp[64 + l],  acc, 0, 0, 0);
            acc = __builtin_amdgcn_mfma_f32_16x16x32_bf16(af[2].v, Bp[128 + l], acc, 0, 0, 0);
            acc = __builtin_amdgcn_mfma_f32_16x16x32_bf16(af[3].v, Bp[192 + l], acc, 0, 0, 0);

            if (active) {
                int col = ct * 16 + colb;
                if (pass) {
                    float bv = bias[col];
#pragma unroll
                    for (int r = 0; r < 4; ++r) {
                        int row = row0 + rq + r;
                        if (row < n) fOut[(size_t)row * N_HID + col] = acc[r] + bv;
                    }
                } else {
#pragma unroll
                    for (int r = 0; r < 4; ++r) {
                        int row = row0 + rq + r;
                        if (row < n) msgOut[(size_t)row * N_HID + col] = f2bf(acc[r]);
                    }
                }
            }
        }
    }
}

// ---------------------------------------------------------------------------
// Bucket scatter over DENSE per-slice lists. slice = blockIdx&7 (XCD-affine
// under round-robin dispatch) -> cnt/bucket lines written from ~one XCD.
// ---------------------------------------------------------------------------
__global__ __launch_bounds__(256) void bucket_scatter2(
    const unsigned int* __restrict__ part,
    const int* __restrict__ sbase,
    int* __restrict__ cnt,
    int* __restrict__ bucket,
    int* __restrict__ ovfn,
    long long* __restrict__ ovf)
{
    const int slice = blockIdx.x & 7;
    const int g     = blockIdx.x >> 3;
    const int nG    = (int)(gridDim.x >> 3);
    const int lo    = sbase[slice];
    const int hi    = sbase[slice + 1];
    const int m     = hi - lo;

    const int chunk = (m + nG - 1) / nG;
    const int e0 = lo + g * chunk;
    int e1 = e0 + chunk; if (e1 > hi) e1 = hi;

    for (int e = e0 + (int)threadIdx.x; e < e1; e += 256) {
        unsigned int pk = part[e];
        int d = (int)(pk >> 16);
        int s = (int)(pk & 0xffffu);
        int c = atomicAdd(&cnt[d], 1);
        if (c < CAP) {
            bucket[(size_t)d * CAP + c] = s;
        } else {
            int o = atomicAdd(ovfn, 1);
            if (o < OVF_CAP) ovf[o] = ((long long)d << 32) | (unsigned int)s;
        }
    }
}

// ---------------------------------------------------------------------------
// Per-node gather(bf16 msg) + mean + self(f32, already in out) + relu.
// One wave per node; lane reads one uint = 2 bf16 (256B/row coalesced).
// ---------------------------------------------------------------------------
__global__ __launch_bounds__(256) void gather_finish(
    const int* __restrict__ cnt,
    const int* __restrict__ bucket,
    const int* __restrict__ ovfn,
    const long long* __restrict__ ovf,
    const unsigned short* __restrict__ msg,
    float* __restrict__ out,
    int n)
{
    int node = blockIdx.x * 4 + (threadIdx.x >> 6);
    if (node >= n) return;
    int lane = threadIdx.x & 63;
    int deg  = cnt[node];
    int m    = deg < CAP ? deg : CAP;

    const int* bk = &bucket[(size_t)node * CAP];
    const unsigned int* m32 = (const unsigned int*)msg;   // 64 uints per row

    float ax = 0.f, ay = 0.f;
    int i = 0;
    for (; i + 4 <= m; i += 4) {
        int s0 = bk[i + 0], s1 = bk[i + 1], s2 = bk[i + 2], s3 = bk[i + 3];
        unsigned int v0 = m32[(size_t)s0 * 64 + lane];
        unsigned int v1 = m32[(size_t)s1 * 64 + lane];
        unsigned int v2 = m32[(size_t)s2 * 64 + lane];
        unsigned int v3 = m32[(size_t)s3 * 64 + lane];
        ax += bf2f(v0 & 0xffffu) + bf2f(v1 & 0xffffu) + bf2f(v2 & 0xffffu) + bf2f(v3 & 0xffffu);
        ay += bf2f(v0 >> 16)     + bf2f(v1 >> 16)     + bf2f(v2 >> 16)     + bf2f(v3 >> 16);
    }
    for (; i < m; ++i) {
        unsigned int v = m32[(size_t)bk[i] * 64 + lane];
        ax += bf2f(v & 0xffffu);
        ay += bf2f(v >> 16);
    }

    if (deg > CAP) {                 // exact fallback; never taken on this data
        int no = *ovfn; if (no > OVF_CAP) no = OVF_CAP;
        for (int o = 0; o < no; ++o) {
            long long pk = ovf[o];
            if ((int)(pk >> 32) == node) {
                unsigned int v = m32[(size_t)(unsigned int)pk * 64 + lane];
                ax += bf2f(v & 0xffffu);
                ay += bf2f(v >> 16);
            }
        }
    }

    float sc = deg > 0 ? 1.0f / (float)deg : 0.f;

    float2* o2 = (float2*)out;
    float2 sv  = o2[(size_t)node * 64 + lane];
    float2 r;
    r.x = fmaxf(sv.x + ax * sc, 0.f);
    r.y = fmaxf(sv.y + ay * sc, 0.f);
    o2[(size_t)node * 64 + lane] = r;
}

// ---------------------------------------------------------------------------
extern "C" void kernel_launch(void* const* d_in, const int* in_sizes, int n_in,
                              void* d_out, int out_size, void* d_ws, size_t ws_size,
                              hipStream_t stream)
{
    const float* h   = (const float*)d_in[0];
    const int*   src = (const int*)d_in[1];
    const int*   dst = (const int*)d_in[2];
    const float* We  = (const float*)d_in[3];
    const float* Ws  = (const float*)d_in[4];
    const float* bs  = (const float*)d_in[5];
    float*       out = (float*)d_out;

    const int n   = in_sizes[0] / N_HID;    // 50000
    const int E   = in_sizes[1];            // 800000
    const int nrt = (n + 15) / 16;          // 3125 row tiles

    // workspace (~33 MB of the 256 MiB d_ws)
    unsigned short* msg = (unsigned short*)d_ws;              // n*128 bf16  (12.8 MB)
    int*   bucket = (int*)(msg + (size_t)n * N_HID);          // n*CAP int   (12.8 MB)
    unsigned short* Be  = (unsigned short*)(bucket + (size_t)n * CAP);  // 8*2048
    unsigned short* Bs  = Be + 8 * 2048;                      // 8*2048
    int*  cnt  = (int*)(Bs + 8 * 2048);                       // n
    int*  ovfn = cnt + n;                                     // 1 (+pad)
    long long* ovf = (long long*)(ovfn + 8);                  // OVF_CAP
    int*  blockCnt  = (int*)(ovf + OVF_CAP);                  // PBLK*NSLICE
    int*  blockBase = blockCnt + PBLK * NSLICE;               // PBLK*NSLICE
    int*  sbase     = blockBase + PBLK * NSLICE;              // 9 (+pad)
    unsigned int* part = (unsigned int*)(sbase + 16);         // E u32 (3.2 MB)

    part_count<<<PBLK, 256, 0, stream>>>(dst, blockCnt, cnt, ovfn, E, n);
    scan_fragw<<<17, 256, 0, stream>>>(blockCnt, blockBase, sbase, E, We, Ws, Be, Bs);
    part_scatter<<<PBLK, 256, 0, stream>>>(src, dst, blockBase, part, E, n);
    gemm_fused<<<(nrt + 3) / 4, 256, 0, stream>>>(h, Be, Bs, bs, msg, out, n, nrt);
    bucket_scatter2<<<512, 256, 0, stream>>>(part, sbase, cnt, bucket, ovfn, ovf);
    gather_finish<<<(n + 3) / 4, 256, 0, stream>>>(cnt, bucket, ovfn, ovf, msg, out, n);
}

// Round 11
// 189.419 us; speedup vs baseline: 1.3687x; 1.0188x over previous
//
#include <hip/hip_runtime.h>

#define N_HID 128
#define CAP   64          // bucket slots per node (Poisson(16) degree; overflow handled exactly)
#define OVF_CAP 8192
#define NSLICE 8
#define PBLK   256        // partition grid size (scan kernel scans PBLK*NSLICE counts)
#define LDW   132         // 128 + 4 pad words (breaks frag-read bank conflicts)

typedef short bf16x8 __attribute__((ext_vector_type(8)));
typedef float f32x4  __attribute__((ext_vector_type(4)));

// round-to-nearest-even f32 -> bf16 bits
static __device__ __forceinline__ unsigned short f2bf(float f)
{
    unsigned int u = __float_as_uint(f);
    u = (u + 0x7fffu + ((u >> 16) & 1u)) >> 16;
    return (unsigned short)u;
}
static __device__ __forceinline__ unsigned int pack2(float a, float b)
{
    return (unsigned int)f2bf(a) | ((unsigned int)f2bf(b) << 16);
}
static __device__ __forceinline__ float bf2f(unsigned int bits16)
{
    return __uint_as_float(bits16 << 16);
}
// slice map: ANY deterministic d->[0,8) works as long as count & scatter use
// the IDENTICAL expression. Float multiply avoids per-edge 64-bit mul+div.
static __device__ __forceinline__ int slice_of(int d, float sln)
{
    int sl = (int)((float)d * sln);
    return sl > NSLICE - 1 ? NSLICE - 1 : sl;
}

// ---------------------------------------------------------------------------
// K1: blocks [0,PBLK) = per-block per-slice edge counts (no atomics) + zero
// cnt/ovfn. Blocks [PBLK,PBLK+16) = weight fragmentize (We 0-7, Ws 8-15).
// Frag layout per 16-row tile rt: [kc 0..3][lane 0..63][j 0..7] ushort,
// lane = ((k>>3)&3)*16 + (row&15), j = k&7.
// ---------------------------------------------------------------------------
__global__ __launch_bounds__(256) void count_fragw(
    const int* __restrict__ dst, int* __restrict__ blockCnt,
    int* __restrict__ cnt, int* __restrict__ ovfn, int E, int n, float sln,
    const float* __restrict__ We, const float* __restrict__ Ws,
    unsigned short* __restrict__ Be, unsigned short* __restrict__ Bs)
{
    int t = threadIdx.x, b = blockIdx.x;

    if (b >= PBLK) {   // ---- weight fragmentize ----
        int bb = b - PBLK;
        const float* srcw = (bb < 8) ? We : Ws;
        unsigned short* dstF = (bb < 8) ? Be : Bs;
        int rt = bb & 7;
        int kc = t >> 6, l = t & 63, m = l & 15, q = l >> 4;
        const float* p = &srcw[(size_t)(rt * 16 + m) * N_HID + kc * 32 + q * 8];
        float4 v0 = *(const float4*)p;
        float4 v1 = *(const float4*)(p + 4);
        uint4 pk;
        pk.x = pack2(v0.x, v0.y);
        pk.y = pack2(v0.z, v0.w);
        pk.z = pack2(v1.x, v1.y);
        pk.w = pack2(v1.z, v1.w);
        *(uint4*)&dstF[(size_t)rt * 2048 + kc * 512 + l * 8] = pk;
        return;
    }

    // ---- edge slice counts ----
    for (int i = b * 256 + t; i < n; i += PBLK * 256) cnt[i] = 0;
    if (b == 0 && t == 0) *ovfn = 0;

    int c[NSLICE];
#pragma unroll
    for (int s = 0; s < NSLICE; ++s) c[s] = 0;

    for (int e = b * 256 + t; e < E; e += PBLK * 256) {
        int sl = slice_of(dst[e], sln);
#pragma unroll
        for (int s = 0; s < NSLICE; ++s) c[s] += (sl == s);
    }

    __shared__ int red[NSLICE * 4];
    int lane = t & 63, wid = t >> 6;
#pragma unroll
    for (int s = 0; s < NSLICE; ++s) {
        int v = c[s];
#pragma unroll
        for (int off = 32; off; off >>= 1) v += __shfl_down(v, off);
        if (lane == 0) red[s * 4 + wid] = v;
    }
    __syncthreads();
    if (t < NSLICE)
        blockCnt[t * PBLK + b] = red[t*4+0] + red[t*4+1] + red[t*4+2] + red[t*4+3];
}

// ---------------------------------------------------------------------------
// K2: block 0 = exclusive scan of PBLK*NSLICE counts -> blockBase + sbase[9];
// blocks 1.. = fused dual GEMM with in-kernel A-fragmentization.
// 4 waves/block, one 16-row tile per wave: stage 16x128 f32 coalesced into
// padded LDS, build A-frags in registers once, run both B-passes
// (We -> msg bf16, Ws -> out f32 + bias). D: col=lane&15, row=(lane>>4)*4+r.
// ---------------------------------------------------------------------------
__global__ __launch_bounds__(256) void scan_gemm(
    const int* __restrict__ blockCnt, int* __restrict__ blockBase,
    int* __restrict__ sbase, int E,
    const float* __restrict__ h,
    const unsigned short* __restrict__ Be,
    const unsigned short* __restrict__ Bsf,
    const float* __restrict__ bias,
    unsigned short* __restrict__ msgOut,
    float* __restrict__ fOut,
    int n, int nrt)
{
    __shared__ float As[4][16 * LDW];   // 33 KB (gemm path)

    int t = threadIdx.x;
    if (blockIdx.x == 0) {   // ---- scan ----
        __shared__ int wsm[4];
        int lane = t & 63, wid = t >> 6;
        int v[8]; int s = 0;
#pragma unroll
        for (int i = 0; i < 8; ++i) { v[i] = blockCnt[t * 8 + i]; s += v[i]; }
        int val = s;
#pragma unroll
        for (int off = 1; off < 64; off <<= 1) {
            int y = __shfl_up(val, off);
            if (lane >= off) val += y;
        }
        if (lane == 63) wsm[wid] = val;
        __syncthreads();
        if (t == 0) { int a = 0; for (int w = 0; w < 4; ++w) { int tmp = wsm[w]; wsm[w] = a; a += tmp; } }
        __syncthreads();
        int excl = wsm[wid] + val - s;
#pragma unroll
        for (int i = 0; i < 8; ++i) { int tv = v[i]; blockBase[t * 8 + i] = excl; excl += tv; }
        __syncthreads();
        if (t < NSLICE) sbase[t] = blockBase[t * PBLK];
        if (t == 0)     sbase[NSLICE] = E;
        return;
    }

    // ---- gemm ----
    int w = t >> 6, l = t & 63;
    int rt = (blockIdx.x - 1) * 4 + w;
    bool active = rt < nrt;
    int rtc = active ? rt : nrt - 1;
    int row0 = rtc * 16;

    float* A = As[w];
#pragma unroll
    for (int it = 0; it < 8; ++it) {
        int f  = it * 64 + l;
        int r  = f >> 5;
        int c4 = (f & 31) * 4;
        int gr = row0 + r; if (gr > n - 1) gr = n - 1;
        *(float4*)&A[r * LDW + c4] = *(const float4*)&h[(size_t)gr * N_HID + c4];
    }
    __syncthreads();   // all waves staged (uniform: no early returns)

    int m = l & 15, q = l >> 4;
    union { uint4 u; bf16x8 v; } af[4];
#pragma unroll
    for (int kc = 0; kc < 4; ++kc) {
        const float* p = &A[m * LDW + kc * 32 + q * 8];
        float4 v0 = *(const float4*)p;
        float4 v1 = *(const float4*)(p + 4);
        af[kc].u.x = pack2(v0.x, v0.y);
        af[kc].u.y = pack2(v0.z, v0.w);
        af[kc].u.z = pack2(v1.x, v1.y);
        af[kc].u.w = pack2(v1.z, v1.w);
    }

    const int colb = l & 15;
    const int rq   = (l >> 4) * 4;

#pragma unroll 1
    for (int pass = 0; pass < 2; ++pass) {
        const unsigned short* Bfrag = pass ? Bsf : Be;
#pragma unroll
        for (int ct = 0; ct < 8; ++ct) {
            const bf16x8* Bp = (const bf16x8*)(Bfrag + (size_t)ct * 2048);
            f32x4 acc = {0.f, 0.f, 0.f, 0.f};
            acc = __builtin_amdgcn_mfma_f32_16x16x32_bf16(af[0].v, Bp[l],       acc, 0, 0, 0);
            acc = __builtin_amdgcn_mfma_f32_16x16x32_bf16(af[1].v, Bp[64 + l],  acc, 0, 0, 0);
            acc = __builtin_amdgcn_mfma_f32_16x16x32_bf16(af[2].v, Bp[128 + l], acc, 0, 0, 0);
            acc = __builtin_amdgcn_mfma_f32_16x16x32_bf16(af[3].v, Bp[192 + l], acc, 0, 0, 0);

            if (active) {
                int col = ct * 16 + colb;
                if (pass) {
                    float bv = bias[col];
#pragma unroll
                    for (int r = 0; r < 4; ++r) {
                        int row = row0 + rq + r;
                        if (row < n) fOut[(size_t)row * N_HID + col] = acc[r] + bv;
                    }
                } else {
#pragma unroll
                    for (int r = 0; r < 4; ++r) {
                        int row = row0 + rq + r;
                        if (row < n) msgOut[(size_t)row * N_HID + col] = f2bf(acc[r]);
                    }
                }
            }
        }
    }
}

// ---------------------------------------------------------------------------
// K3: scatter edges into dense per-slice queues using precomputed
// per-(block,slice) bases — only LDS atomics. Packed u32 (d<<16)|s (n<=65536).
// ---------------------------------------------------------------------------
__global__ __launch_bounds__(256) void part_scatter(
    const int* __restrict__ src, const int* __restrict__ dst,
    const int* __restrict__ blockBase, unsigned int* __restrict__ part,
    int E, int n, float sln)
{
    __shared__ int cur[NSLICE];
    int t = threadIdx.x, b = blockIdx.x;
    if (t < NSLICE) cur[t] = blockBase[t * PBLK + b];
    __syncthreads();
    for (int e = b * 256 + t; e < E; e += PBLK * 256) {
        int d = dst[e], s = src[e];
        int sl  = slice_of(d, sln);
        int pos = atomicAdd(&cur[sl], 1);
        part[pos] = ((unsigned int)d << 16) | (unsigned int)s;
    }
}

// ---------------------------------------------------------------------------
// K4: bucket scatter over DENSE per-slice lists. slice = blockIdx&7
// (XCD-affine under round-robin dispatch) -> cnt/bucket lines written from
// ~one XCD. Bucket entries are ushort (src < 65536): half the traffic.
// ---------------------------------------------------------------------------
__global__ __launch_bounds__(256) void bucket_scatter2(
    const unsigned int* __restrict__ part,
    const int* __restrict__ sbase,
    int* __restrict__ cnt,
    unsigned short* __restrict__ bucket,
    int* __restrict__ ovfn,
    long long* __restrict__ ovf)
{
    const int slice = blockIdx.x & 7;
    const int g     = blockIdx.x >> 3;
    const int nG    = (int)(gridDim.x >> 3);
    const int lo    = sbase[slice];
    const int hi    = sbase[slice + 1];
    const int m     = hi - lo;

    const int chunk = (m + nG - 1) / nG;
    const int e0 = lo + g * chunk;
    int e1 = e0 + chunk; if (e1 > hi) e1 = hi;

    for (int e = e0 + (int)threadIdx.x; e < e1; e += 256) {
        unsigned int pk = part[e];
        int d = (int)(pk >> 16);
        int s = (int)(pk & 0xffffu);
        int c = atomicAdd(&cnt[d], 1);
        if (c < CAP) {
            bucket[(size_t)d * CAP + c] = (unsigned short)s;
        } else {
            int o = atomicAdd(ovfn, 1);
            if (o < OVF_CAP) ovf[o] = ((long long)d << 32) | (unsigned int)s;
        }
    }
}

// ---------------------------------------------------------------------------
// K5: per-node gather(bf16 msg) + mean + self(f32, already in out) + relu.
// One wave per node; lane reads one uint = 2 bf16 (256B/row coalesced).
// Bucket read as ushort4 (8B per 4 edges).
// ---------------------------------------------------------------------------
__global__ __launch_bounds__(256) void gather_finish(
    const int* __restrict__ cnt,
    const unsigned short* __restrict__ bucket,
    const int* __restrict__ ovfn,
    const long long* __restrict__ ovf,
    const unsigned short* __restrict__ msg,
    float* __restrict__ out,
    int n)
{
    int node = blockIdx.x * 4 + (threadIdx.x >> 6);
    if (node >= n) return;
    int lane = threadIdx.x & 63;
    int deg  = cnt[node];
    int m    = deg < CAP ? deg : CAP;

    const unsigned short* bk = &bucket[(size_t)node * CAP];
    const unsigned int* m32 = (const unsigned int*)msg;   // 64 uints per row

    float ax = 0.f, ay = 0.f;
    int i = 0;
    for (; i + 4 <= m; i += 4) {
        ushort4 ss = *(const ushort4*)&bk[i];
        unsigned int v0 = m32[(size_t)ss.x * 64 + lane];
        unsigned int v1 = m32[(size_t)ss.y * 64 + lane];
        unsigned int v2 = m32[(size_t)ss.z * 64 + lane];
        unsigned int v3 = m32[(size_t)ss.w * 64 + lane];
        ax += bf2f(v0 & 0xffffu) + bf2f(v1 & 0xffffu) + bf2f(v2 & 0xffffu) + bf2f(v3 & 0xffffu);
        ay += bf2f(v0 >> 16)     + bf2f(v1 >> 16)     + bf2f(v2 >> 16)     + bf2f(v3 >> 16);
    }
    for (; i < m; ++i) {
        unsigned int v = m32[(size_t)bk[i] * 64 + lane];
        ax += bf2f(v & 0xffffu);
        ay += bf2f(v >> 16);
    }

    if (deg > CAP) {                 // exact fallback; never taken on this data
        int no = *ovfn; if (no > OVF_CAP) no = OVF_CAP;
        for (int o = 0; o < no; ++o) {
            long long pk = ovf[o];
            if ((int)(pk >> 32) == node) {
                unsigned int v = m32[(size_t)(unsigned int)pk * 64 + lane];
                ax += bf2f(v & 0xffffu);
                ay += bf2f(v >> 16);
            }
        }
    }

    float sc = deg > 0 ? 1.0f / (float)deg : 0.f;

    float2* o2 = (float2*)out;
    float2 sv  = o2[(size_t)node * 64 + lane];
    float2 r;
    r.x = fmaxf(sv.x + ax * sc, 0.f);
    r.y = fmaxf(sv.y + ay * sc, 0.f);
    o2[(size_t)node * 64 + lane] = r;
}

// ---------------------------------------------------------------------------
extern "C" void kernel_launch(void* const* d_in, const int* in_sizes, int n_in,
                              void* d_out, int out_size, void* d_ws, size_t ws_size,
                              hipStream_t stream)
{
    const float* h   = (const float*)d_in[0];
    const int*   src = (const int*)d_in[1];
    const int*   dst = (const int*)d_in[2];
    const float* We  = (const float*)d_in[3];
    const float* Ws  = (const float*)d_in[4];
    const float* bs  = (const float*)d_in[5];
    float*       out = (float*)d_out;

    const int n   = in_sizes[0] / N_HID;    // 50000
    const int E   = in_sizes[1];            // 800000
    const int nrt = (n + 15) / 16;          // 3125 row tiles
    const float sln = (float)NSLICE / (float)n;

    // workspace (~27 MB of the 256 MiB d_ws)
    unsigned short* msg = (unsigned short*)d_ws;              // n*128 bf16  (12.8 MB)
    unsigned short* bucket = msg + (size_t)n * N_HID;         // n*CAP ushort (6.4 MB)
    unsigned short* Be  = bucket + (size_t)n * CAP;           // 8*2048
    unsigned short* Bs  = Be + 8 * 2048;                      // 8*2048
    int*  cnt  = (int*)(Bs + 8 * 2048);                       // n
    int*  ovfn = cnt + n;                                     // 1 (+pad)
    long long* ovf = (long long*)(ovfn + 8);                  // OVF_CAP
    int*  blockCnt  = (int*)(ovf + OVF_CAP);                  // PBLK*NSLICE
    int*  blockBase = blockCnt + PBLK * NSLICE;               // PBLK*NSLICE
    int*  sbase     = blockBase + PBLK * NSLICE;              // 9 (+pad)
    unsigned int* part = (unsigned int*)(sbase + 16);         // E u32 (3.2 MB)

    count_fragw<<<PBLK + 16, 256, 0, stream>>>(dst, blockCnt, cnt, ovfn, E, n, sln,
                                               We, Ws, Be, Bs);
    scan_gemm<<<1 + (nrt + 3) / 4, 256, 0, stream>>>(blockCnt, blockBase, sbase, E,
                                                     h, Be, Bs, bs, msg, out, n, nrt);
    part_scatter<<<PBLK, 256, 0, stream>>>(src, dst, blockBase, part, E, n, sln);
    bucket_scatter2<<<1024, 256, 0, stream>>>(part, sbase, cnt, bucket, ovfn, ovf);
    gather_finish<<<(n + 3) / 4, 256, 0, stream>>>(cnt, bucket, ovfn, ovf, msg, out, n);
}

// Round 12
// 189.031 us; speedup vs baseline: 1.3715x; 1.0021x over previous
//
#include <hip/hip_runtime.h>

#define N_HID 128
#define CAP   32          // bucket slots per node = exactly one 64B line (ushort)
#define OVF_CAP 8192
#define NSLICE 8
#define PBLK   256        // partition grid size (scan kernel scans PBLK*NSLICE counts)

typedef short bf16x8 __attribute__((ext_vector_type(8)));
typedef float f32x4  __attribute__((ext_vector_type(4)));

// round-to-nearest-even f32 -> bf16 bits
static __device__ __forceinline__ unsigned short f2bf(float f)
{
    unsigned int u = __float_as_uint(f);
    u = (u + 0x7fffu + ((u >> 16) & 1u)) >> 16;
    return (unsigned short)u;
}
static __device__ __forceinline__ unsigned int pack2(float a, float b)
{
    return (unsigned int)f2bf(a) | ((unsigned int)f2bf(b) << 16);
}
static __device__ __forceinline__ float bf2f(unsigned int bits16)
{
    return __uint_as_float(bits16 << 16);
}
// slice map: ANY deterministic d->[0,8) works as long as count & scatter use
// the IDENTICAL expression.
static __device__ __forceinline__ int slice_of(int d, float sln)
{
    int sl = (int)((float)d * sln);
    return sl > NSLICE - 1 ? NSLICE - 1 : sl;
}

// ---------------------------------------------------------------------------
// K1: blocks [0,PBLK) = per-block per-slice edge counts (no atomics) + zero
// cnt/ovfn. Blocks [PBLK,PBLK+16) = weight fragmentize (We 0-7, Ws 8-15).
// Frag layout per 16-row tile rt: [kc 0..3][lane 0..63][j 0..7] ushort,
// lane = ((k>>3)&3)*16 + (row&15), j = k&7.
// ---------------------------------------------------------------------------
__global__ __launch_bounds__(256) void count_fragw(
    const int* __restrict__ dst, int* __restrict__ blockCnt,
    int* __restrict__ cnt, int* __restrict__ ovfn, int E, int n, float sln,
    const float* __restrict__ We, const float* __restrict__ Ws,
    unsigned short* __restrict__ Be, unsigned short* __restrict__ Bs)
{
    int t = threadIdx.x, b = blockIdx.x;

    if (b >= PBLK) {   // ---- weight fragmentize ----
        int bb = b - PBLK;
        const float* srcw = (bb < 8) ? We : Ws;
        unsigned short* dstF = (bb < 8) ? Be : Bs;
        int rt = bb & 7;
        int kc = t >> 6, l = t & 63, m = l & 15, q = l >> 4;
        const float* p = &srcw[(size_t)(rt * 16 + m) * N_HID + kc * 32 + q * 8];
        float4 v0 = *(const float4*)p;
        float4 v1 = *(const float4*)(p + 4);
        uint4 pk;
        pk.x = pack2(v0.x, v0.y);
        pk.y = pack2(v0.z, v0.w);
        pk.z = pack2(v1.x, v1.y);
        pk.w = pack2(v1.z, v1.w);
        *(uint4*)&dstF[(size_t)rt * 2048 + kc * 512 + l * 8] = pk;
        return;
    }

    // ---- edge slice counts ----
    for (int i = b * 256 + t; i < n; i += PBLK * 256) cnt[i] = 0;
    if (b == 0 && t == 0) *ovfn = 0;

    int c[NSLICE];
#pragma unroll
    for (int s = 0; s < NSLICE; ++s) c[s] = 0;

    for (int e = b * 256 + t; e < E; e += PBLK * 256) {
        int sl = slice_of(dst[e], sln);
#pragma unroll
        for (int s = 0; s < NSLICE; ++s) c[s] += (sl == s);
    }

    __shared__ int red[NSLICE * 4];
    int lane = t & 63, wid = t >> 6;
#pragma unroll
    for (int s = 0; s < NSLICE; ++s) {
        int v = c[s];
#pragma unroll
        for (int off = 32; off; off >>= 1) v += __shfl_down(v, off);
        if (lane == 0) red[s * 4 + wid] = v;
    }
    __syncthreads();
    if (t < NSLICE)
        blockCnt[t * PBLK + b] = red[t*4+0] + red[t*4+1] + red[t*4+2] + red[t*4+3];
}

// ---------------------------------------------------------------------------
// K2: block 0 = exclusive scan of PBLK*NSLICE counts -> blockBase + sbase[9];
// blocks 1.. = cast h f32 -> hbf bf16 row-major (each thread 8 elems).
// ---------------------------------------------------------------------------
__global__ __launch_bounds__(256) void scan_cast(
    const int* __restrict__ blockCnt, int* __restrict__ blockBase,
    int* __restrict__ sbase, int E,
    const float* __restrict__ h, unsigned short* __restrict__ hbf, int total)
{
    int t = threadIdx.x;
    if (blockIdx.x == 0) {   // ---- scan ----
        __shared__ int wsm[4];
        int lane = t & 63, wid = t >> 6;
        int v[8]; int s = 0;
#pragma unroll
        for (int i = 0; i < 8; ++i) { v[i] = blockCnt[t * 8 + i]; s += v[i]; }
        int val = s;
#pragma unroll
        for (int off = 1; off < 64; off <<= 1) {
            int y = __shfl_up(val, off);
            if (lane >= off) val += y;
        }
        if (lane == 63) wsm[wid] = val;
        __syncthreads();
        if (t == 0) { int a = 0; for (int w = 0; w < 4; ++w) { int tmp = wsm[w]; wsm[w] = a; a += tmp; } }
        __syncthreads();
        int excl = wsm[wid] + val - s;
#pragma unroll
        for (int i = 0; i < 8; ++i) { int tv = v[i]; blockBase[t * 8 + i] = excl; excl += tv; }
        __syncthreads();
        if (t < NSLICE) sbase[t] = blockBase[t * PBLK];
        if (t == 0)     sbase[NSLICE] = E;
        return;
    }
    int idx = ((int)blockIdx.x - 1) * 2048 + t * 8;
    if (idx + 8 <= total) {
        float4 v0 = *(const float4*)&h[idx];
        float4 v1 = *(const float4*)&h[idx + 4];
        uint4 pk;
        pk.x = pack2(v0.x, v0.y);
        pk.y = pack2(v0.z, v0.w);
        pk.z = pack2(v1.x, v1.y);
        pk.w = pack2(v1.z, v1.w);
        *(uint4*)&hbf[idx] = pk;
    }
}

// ---------------------------------------------------------------------------
// K3: scatter edges into dense per-slice queues using precomputed
// per-(block,slice) bases — only LDS atomics. Packed u32 (d<<16)|s (n<=65536).
// ---------------------------------------------------------------------------
__global__ __launch_bounds__(256) void part_scatter(
    const int* __restrict__ src, const int* __restrict__ dst,
    const int* __restrict__ blockBase, unsigned int* __restrict__ part,
    int E, int n, float sln)
{
    __shared__ int cur[NSLICE];
    int t = threadIdx.x, b = blockIdx.x;
    if (t < NSLICE) cur[t] = blockBase[t * PBLK + b];
    __syncthreads();
    for (int e = b * 256 + t; e < E; e += PBLK * 256) {
        int d = dst[e], s = src[e];
        int sl  = slice_of(d, sln);
        int pos = atomicAdd(&cur[sl], 1);
        part[pos] = ((unsigned int)d << 16) | (unsigned int)s;
    }
}

// ---------------------------------------------------------------------------
// K4: bucket scatter over DENSE per-slice lists. slice = blockIdx&7
// (XCD-affine under round-robin dispatch) -> cnt/bucket lines written from
// ~one XCD. ushort entries, CAP=32 -> one 64B line per node.
// ---------------------------------------------------------------------------
__global__ __launch_bounds__(256) void bucket_scatter2(
    const unsigned int* __restrict__ part,
    const int* __restrict__ sbase,
    int* __restrict__ cnt,
    unsigned short* __restrict__ bucket,
    int* __restrict__ ovfn,
    long long* __restrict__ ovf)
{
    const int slice = blockIdx.x & 7;
    const int g     = blockIdx.x >> 3;
    const int nG    = (int)(gridDim.x >> 3);
    const int lo    = sbase[slice];
    const int hi    = sbase[slice + 1];
    const int m     = hi - lo;

    const int chunk = (m + nG - 1) / nG;
    const int e0 = lo + g * chunk;
    int e1 = e0 + chunk; if (e1 > hi) e1 = hi;

    for (int e = e0 + (int)threadIdx.x; e < e1; e += 256) {
        unsigned int pk = part[e];
        int d = (int)(pk >> 16);
        int s = (int)(pk & 0xffffu);
        int c = atomicAdd(&cnt[d], 1);
        if (c < CAP) {
            bucket[(size_t)d * CAP + c] = (unsigned short)s;
        } else {
            int o = atomicAdd(ovfn, 1);
            if (o < OVF_CAP) ovf[o] = ((long long)d << 32) | (unsigned int)s;
        }
    }
}

// ---------------------------------------------------------------------------
// K5: gather + MEAN on hbf (linearity: mean before the edge-GEMM).
// One wave per node; lane sums cols 2l,2l+1 across neighbor rows, divides by
// deg, writes hagg DIRECTLY in A-fragment order:
// k=2l -> kc=l>>4, q=(l>>2)&3, j=(l&3)*2; slot = rt*2048+kc*512+(q*16+m)*8+j.
// ---------------------------------------------------------------------------
__global__ __launch_bounds__(256) void gather_mean(
    const int* __restrict__ cnt,
    const unsigned short* __restrict__ bucket,
    const int* __restrict__ ovfn,
    const long long* __restrict__ ovf,
    const unsigned short* __restrict__ hbf,
    unsigned short* __restrict__ hagg,
    int n)
{
    int node = blockIdx.x * 4 + (threadIdx.x >> 6);
    if (node >= n) return;
    int lane = threadIdx.x & 63;
    int deg  = cnt[node];
    int m    = deg < CAP ? deg : CAP;

    const unsigned short* bk = &bucket[(size_t)node * CAP];
    const unsigned int* h32 = (const unsigned int*)hbf;   // 64 uints per row

    float ax = 0.f, ay = 0.f;
    int i = 0;
    for (; i + 4 <= m; i += 4) {
        ushort4 ss = *(const ushort4*)&bk[i];
        unsigned int v0 = h32[(size_t)ss.x * 64 + lane];
        unsigned int v1 = h32[(size_t)ss.y * 64 + lane];
        unsigned int v2 = h32[(size_t)ss.z * 64 + lane];
        unsigned int v3 = h32[(size_t)ss.w * 64 + lane];
        ax += bf2f(v0 & 0xffffu) + bf2f(v1 & 0xffffu) + bf2f(v2 & 0xffffu) + bf2f(v3 & 0xffffu);
        ay += bf2f(v0 >> 16)     + bf2f(v1 >> 16)     + bf2f(v2 >> 16)     + bf2f(v3 >> 16);
    }
    for (; i < m; ++i) {
        unsigned int v = h32[(size_t)bk[i] * 64 + lane];
        ax += bf2f(v & 0xffffu);
        ay += bf2f(v >> 16);
    }

    if (deg > CAP) {                 // exact fallback; ~5 nodes on this data
        int no = *ovfn; if (no > OVF_CAP) no = OVF_CAP;
        for (int o = 0; o < no; ++o) {
            long long pk = ovf[o];
            if ((int)(pk >> 32) == node) {
                unsigned int v = h32[(size_t)(unsigned int)pk * 64 + lane];
                ax += bf2f(v & 0xffffu);
                ay += bf2f(v >> 16);
            }
        }
    }

    float sc = deg > 0 ? 1.0f / (float)deg : 0.f;

    // write in A-frag order
    int rt = node >> 4, mm = node & 15;
    int kc = lane >> 4, q = (lane >> 2) & 3, j = (lane & 3) * 2;
    unsigned int pk = pack2(ax * sc, ay * sc);
    *(unsigned int*)&hagg[(size_t)rt * 2048 + kc * 512 + (q * 16 + mm) * 8 + j] = pk;
}

// ---------------------------------------------------------------------------
// K6: final fused GEMM, no LDS. One wave per 16-row tile.
// out = relu(hbf·Ws^T + b + hagg·We^T). hbf A-frags load as permuted-
// contiguous 4KB tiles from row-major; hagg/B frags lane-linear.
// D layout: col = lane&15, row = (lane>>4)*4 + reg.
// ---------------------------------------------------------------------------
__global__ __launch_bounds__(256) void gemm_final(
    const unsigned short* __restrict__ hbf,
    const unsigned short* __restrict__ hagg,
    const unsigned short* __restrict__ Be,
    const unsigned short* __restrict__ Bsf,
    const float* __restrict__ bias,
    float* __restrict__ out,
    int n, int nrt)
{
    int w = (int)((blockIdx.x * blockDim.x + threadIdx.x) >> 6);
    if (w >= nrt) return;
    int l = threadIdx.x & 63;
    int m = l & 15, q = l >> 4;
    int row0 = w * 16;

    // A-frags of hbf: lane(m,q), kc-chunk -> 16B from row-major (permuted-contiguous)
    bf16x8 ah[4];
#pragma unroll
    for (int kc = 0; kc < 4; ++kc) {
        int gr = row0 + m; if (gr > n - 1) gr = n - 1;
        ah[kc] = *(const bf16x8*)&hbf[(size_t)gr * N_HID + kc * 32 + q * 8];
    }
    // A-frags of hagg: lane-linear (written in frag order by gather_mean)
    const bf16x8* Gp = (const bf16x8*)(hagg + (size_t)w * 2048);
    bf16x8 ag0 = Gp[l], ag1 = Gp[64 + l], ag2 = Gp[128 + l], ag3 = Gp[192 + l];

    const int colb = l & 15;
    const int rq   = (l >> 4) * 4;

#pragma unroll
    for (int ct = 0; ct < 8; ++ct) {
        const bf16x8* BpS = (const bf16x8*)(Bsf + (size_t)ct * 2048);
        const bf16x8* BpE = (const bf16x8*)(Be  + (size_t)ct * 2048);
        f32x4 acc = {0.f, 0.f, 0.f, 0.f};
        acc = __builtin_amdgcn_mfma_f32_16x16x32_bf16(ah[0], BpS[l],       acc, 0, 0, 0);
        acc = __builtin_amdgcn_mfma_f32_16x16x32_bf16(ah[1], BpS[64 + l],  acc, 0, 0, 0);
        acc = __builtin_amdgcn_mfma_f32_16x16x32_bf16(ah[2], BpS[128 + l], acc, 0, 0, 0);
        acc = __builtin_amdgcn_mfma_f32_16x16x32_bf16(ah[3], BpS[192 + l], acc, 0, 0, 0);
        acc = __builtin_amdgcn_mfma_f32_16x16x32_bf16(ag0,   BpE[l],       acc, 0, 0, 0);
        acc = __builtin_amdgcn_mfma_f32_16x16x32_bf16(ag1,   BpE[64 + l],  acc, 0, 0, 0);
        acc = __builtin_amdgcn_mfma_f32_16x16x32_bf16(ag2,   BpE[128 + l], acc, 0, 0, 0);
        acc = __builtin_amdgcn_mfma_f32_16x16x32_bf16(ag3,   BpE[192 + l], acc, 0, 0, 0);

        int col = ct * 16 + colb;
        float bv = bias[col];
#pragma unroll
        for (int r = 0; r < 4; ++r) {
            int row = row0 + rq + r;
            if (row < n) out[(size_t)row * N_HID + col] = fmaxf(acc[r] + bv, 0.f);
        }
    }
}

// ---------------------------------------------------------------------------
extern "C" void kernel_launch(void* const* d_in, const int* in_sizes, int n_in,
                              void* d_out, int out_size, void* d_ws, size_t ws_size,
                              hipStream_t stream)
{
    const float* h   = (const float*)d_in[0];
    const int*   src = (const int*)d_in[1];
    const int*   dst = (const int*)d_in[2];
    const float* We  = (const float*)d_in[3];
    const float* Ws  = (const float*)d_in[4];
    const float* bs  = (const float*)d_in[5];
    float*       out = (float*)d_out;

    const int n   = in_sizes[0] / N_HID;    // 50000
    const int E   = in_sizes[1];            // 800000
    const int nrt = (n + 15) / 16;          // 3125 row tiles
    const float sln = (float)NSLICE / (float)n;
    const int total = n * N_HID;

    // workspace (~33 MB of the 256 MiB d_ws)
    unsigned short* hbf  = (unsigned short*)d_ws;             // n*128 bf16 row-major (12.8 MB)
    unsigned short* hagg = hbf + (size_t)n * N_HID;           // nrt*2048 frag order  (12.8 MB)
    unsigned short* bucket = hagg + (size_t)nrt * 2048;       // n*CAP ushort (3.2 MB)
    unsigned short* Be  = bucket + (size_t)n * CAP;           // 8*2048
    unsigned short* Bs  = Be + 8 * 2048;                      // 8*2048
    int*  cnt  = (int*)(Bs + 8 * 2048);                       // n
    int*  ovfn = cnt + n;                                     // 1 (+pad)
    long long* ovf = (long long*)(ovfn + 8);                  // OVF_CAP
    int*  blockCnt  = (int*)(ovf + OVF_CAP);                  // PBLK*NSLICE
    int*  blockBase = blockCnt + PBLK * NSLICE;               // PBLK*NSLICE
    int*  sbase     = blockBase + PBLK * NSLICE;              // 9 (+pad)
    unsigned int* part = (unsigned int*)(sbase + 16);         // E u32 (3.2 MB)

    const int castBlocks = (total + 2047) / 2048;             // 3125

    count_fragw<<<PBLK + 16, 256, 0, stream>>>(dst, blockCnt, cnt, ovfn, E, n, sln,
                                               We, Ws, Be, Bs);
    scan_cast<<<1 + castBlocks, 256, 0, stream>>>(blockCnt, blockBase, sbase, E,
                                                  h, hbf, total);
    part_scatter<<<PBLK, 256, 0, stream>>>(src, dst, blockBase, part, E, n, sln);
    bucket_scatter2<<<1024, 256, 0, stream>>>(part, sbase, cnt, bucket, ovfn, ovf);
    gather_mean<<<(n + 3) / 4, 256, 0, stream>>>(cnt, bucket, ovfn, ovf, hbf, hagg, n);
    gemm_final<<<(nrt + 3) / 4, 256, 0, stream>>>(hbf, hagg, Be, Bs, bs, out, n, nrt);
}

// Round 13
// 186.916 us; speedup vs baseline: 1.3870x; 1.0113x over previous
//
#include <hip/hip_runtime.h>

#define N_HID 128
#define CAP   32          // bucket slots per node = exactly one 64B line (ushort)
#define OVF_CAP 8192
#define NSLICE 8
#define PBLK   256        // partition grid size (scan kernel scans PBLK*NSLICE counts)

typedef short bf16x8 __attribute__((ext_vector_type(8)));
typedef float f32x4  __attribute__((ext_vector_type(4)));

// round-to-nearest-even f32 -> bf16 bits
static __device__ __forceinline__ unsigned short f2bf(float f)
{
    unsigned int u = __float_as_uint(f);
    u = (u + 0x7fffu + ((u >> 16) & 1u)) >> 16;
    return (unsigned short)u;
}
static __device__ __forceinline__ unsigned int pack2(float a, float b)
{
    return (unsigned int)f2bf(a) | ((unsigned int)f2bf(b) << 16);
}
static __device__ __forceinline__ float bf2f(unsigned int bits16)
{
    return __uint_as_float(bits16 << 16);
}
// slice map: ANY deterministic d->[0,8) works as long as count & scatter use
// the IDENTICAL expression.
static __device__ __forceinline__ int slice_of(int d, float sln)
{
    int sl = (int)((float)d * sln);
    return sl > NSLICE - 1 ? NSLICE - 1 : sl;
}

// ---------------------------------------------------------------------------
// K1: blocks [0,PBLK) = per-block per-slice edge counts (no atomics) + zero
// cnt/ovfn. Blocks [PBLK,PBLK+16) = weight fragmentize (We 0-7, Ws 8-15).
// Blocks [PBLK+16, ...) = cast h f32 -> hbf bf16 row-major.
// Frag layout per 16-row tile rt: [kc 0..3][lane 0..63][j 0..7] ushort,
// lane = ((k>>3)&3)*16 + (row&15), j = k&7.
// ---------------------------------------------------------------------------
__global__ __launch_bounds__(256) void count_fragw_cast(
    const int* __restrict__ dst, int* __restrict__ blockCnt,
    int* __restrict__ cnt, int* __restrict__ ovfn, int E, int n, float sln,
    const float* __restrict__ We, const float* __restrict__ Ws,
    unsigned short* __restrict__ Be, unsigned short* __restrict__ Bs,
    const float* __restrict__ h, unsigned short* __restrict__ hbf, int total)
{
    int t = threadIdx.x, b = blockIdx.x;

    if (b >= PBLK + 16) {   // ---- cast h -> hbf ----
        int idx = (b - PBLK - 16) * 2048 + t * 8;
        if (idx + 8 <= total) {
            float4 v0 = *(const float4*)&h[idx];
            float4 v1 = *(const float4*)&h[idx + 4];
            uint4 pk;
            pk.x = pack2(v0.x, v0.y);
            pk.y = pack2(v0.z, v0.w);
            pk.z = pack2(v1.x, v1.y);
            pk.w = pack2(v1.z, v1.w);
            *(uint4*)&hbf[idx] = pk;
        }
        return;
    }

    if (b >= PBLK) {   // ---- weight fragmentize ----
        int bb = b - PBLK;
        const float* srcw = (bb < 8) ? We : Ws;
        unsigned short* dstF = (bb < 8) ? Be : Bs;
        int rt = bb & 7;
        int kc = t >> 6, l = t & 63, m = l & 15, q = l >> 4;
        const float* p = &srcw[(size_t)(rt * 16 + m) * N_HID + kc * 32 + q * 8];
        float4 v0 = *(const float4*)p;
        float4 v1 = *(const float4*)(p + 4);
        uint4 pk;
        pk.x = pack2(v0.x, v0.y);
        pk.y = pack2(v0.z, v0.w);
        pk.z = pack2(v1.x, v1.y);
        pk.w = pack2(v1.z, v1.w);
        *(uint4*)&dstF[(size_t)rt * 2048 + kc * 512 + l * 8] = pk;
        return;
    }

    // ---- edge slice counts ----
    for (int i = b * 256 + t; i < n; i += PBLK * 256) cnt[i] = 0;
    if (b == 0 && t == 0) *ovfn = 0;

    int c[NSLICE];
#pragma unroll
    for (int s = 0; s < NSLICE; ++s) c[s] = 0;

    for (int e = b * 256 + t; e < E; e += PBLK * 256) {
        int sl = slice_of(dst[e], sln);
#pragma unroll
        for (int s = 0; s < NSLICE; ++s) c[s] += (sl == s);
    }

    __shared__ int red[NSLICE * 4];
    int lane = t & 63, wid = t >> 6;
#pragma unroll
    for (int s = 0; s < NSLICE; ++s) {
        int v = c[s];
#pragma unroll
        for (int off = 32; off; off >>= 1) v += __shfl_down(v, off);
        if (lane == 0) red[s * 4 + wid] = v;
    }
    __syncthreads();
    if (t < NSLICE)
        blockCnt[t * PBLK + b] = red[t*4+0] + red[t*4+1] + red[t*4+2] + red[t*4+3];
}

// ---------------------------------------------------------------------------
// K2: exclusive scan of PBLK*NSLICE counts -> blockBase + sbase[9]. 1 block.
// ---------------------------------------------------------------------------
__global__ __launch_bounds__(256) void part_scan(
    const int* __restrict__ blockCnt, int* __restrict__ blockBase,
    int* __restrict__ sbase, int E)
{
    __shared__ int wsm[4];
    int t = threadIdx.x, lane = t & 63, wid = t >> 6;
    int v[8]; int s = 0;
#pragma unroll
    for (int i = 0; i < 8; ++i) { v[i] = blockCnt[t * 8 + i]; s += v[i]; }
    int val = s;
#pragma unroll
    for (int off = 1; off < 64; off <<= 1) {
        int y = __shfl_up(val, off);
        if (lane >= off) val += y;
    }
    if (lane == 63) wsm[wid] = val;
    __syncthreads();
    if (t == 0) { int a = 0; for (int w = 0; w < 4; ++w) { int tmp = wsm[w]; wsm[w] = a; a += tmp; } }
    __syncthreads();
    int excl = wsm[wid] + val - s;
#pragma unroll
    for (int i = 0; i < 8; ++i) { int tv = v[i]; blockBase[t * 8 + i] = excl; excl += tv; }
    __syncthreads();
    if (t < NSLICE) sbase[t] = blockBase[t * PBLK];
    if (t == 0)     sbase[NSLICE] = E;
}

// ---------------------------------------------------------------------------
// K3: scatter edges into dense per-slice queues using precomputed
// per-(block,slice) bases — only LDS atomics. Packed u32 (d<<16)|s (n<=65536).
// ---------------------------------------------------------------------------
__global__ __launch_bounds__(256) void part_scatter(
    const int* __restrict__ src, const int* __restrict__ dst,
    const int* __restrict__ blockBase, unsigned int* __restrict__ part,
    int E, int n, float sln)
{
    __shared__ int cur[NSLICE];
    int t = threadIdx.x, b = blockIdx.x;
    if (t < NSLICE) cur[t] = blockBase[t * PBLK + b];
    __syncthreads();
    for (int e = b * 256 + t; e < E; e += PBLK * 256) {
        int d = dst[e], s = src[e];
        int sl  = slice_of(d, sln);
        int pos = atomicAdd(&cur[sl], 1);
        part[pos] = ((unsigned int)d << 16) | (unsigned int)s;
    }
}

// ---------------------------------------------------------------------------
// K4: bucket scatter over DENSE per-slice lists. slice = blockIdx&7
// (XCD-affine under round-robin dispatch) -> cnt/bucket lines written from
// ~one XCD. ushort entries, CAP=32 -> one 64B line per node.
// ---------------------------------------------------------------------------
__global__ __launch_bounds__(256) void bucket_scatter2(
    const unsigned int* __restrict__ part,
    const int* __restrict__ sbase,
    int* __restrict__ cnt,
    unsigned short* __restrict__ bucket,
    int* __restrict__ ovfn,
    long long* __restrict__ ovf)
{
    const int slice = blockIdx.x & 7;
    const int g     = blockIdx.x >> 3;
    const int nG    = (int)(gridDim.x >> 3);
    const int lo    = sbase[slice];
    const int hi    = sbase[slice + 1];
    const int m     = hi - lo;

    const int chunk = (m + nG - 1) / nG;
    const int e0 = lo + g * chunk;
    int e1 = e0 + chunk; if (e1 > hi) e1 = hi;

    for (int e = e0 + (int)threadIdx.x; e < e1; e += 256) {
        unsigned int pk = part[e];
        int d = (int)(pk >> 16);
        int s = (int)(pk & 0xffffu);
        int c = atomicAdd(&cnt[d], 1);
        if (c < CAP) {
            bucket[(size_t)d * CAP + c] = (unsigned short)s;
        } else {
            int o = atomicAdd(ovfn, 1);
            if (o < OVF_CAP) ovf[o] = ((long long)d << 32) | (unsigned int)s;
        }
    }
}

// ---------------------------------------------------------------------------
// K5: gather + MEAN on hbf, XCD-AFFINE: block's slice = blockIdx&7 matches
// bucket_scatter2's writer slice, so cnt/bucket lines are read from the L2
// that owns them. Writes hagg directly in A-fragment order:
// k=2l -> kc=l>>4, q=(l>>2)&3, j=(l&3)*2; slot = rt*2048+kc*512+(q*16+m)*8+j.
// ---------------------------------------------------------------------------
__global__ __launch_bounds__(256) void gather_mean(
    const int* __restrict__ cnt,
    const unsigned short* __restrict__ bucket,
    const int* __restrict__ ovfn,
    const long long* __restrict__ ovf,
    const unsigned short* __restrict__ hbf,
    unsigned short* __restrict__ hagg,
    int n, float sln)
{
    // slice-affine node mapping (must cover [0,n) exactly once)
    const int slice = blockIdx.x & 7;
    const int g     = blockIdx.x >> 3;
    const int lo    = (int)(((long long)slice * n) / NSLICE);
    const int hi    = (int)(((long long)(slice + 1) * n) / NSLICE);
    int node = lo + g * 4 + ((int)threadIdx.x >> 6);
    if (node >= hi) return;
    // NOTE: this lo/hi split MUST match slice_of() bucket ownership only for
    // locality, not correctness — every node in [0,n) is covered exactly once.

    int lane = threadIdx.x & 63;
    int deg  = cnt[node];
    int m    = deg < CAP ? deg : CAP;

    const unsigned short* bk = &bucket[(size_t)node * CAP];
    const unsigned int* h32 = (const unsigned int*)hbf;   // 64 uints per row

    float ax = 0.f, ay = 0.f;
    int i = 0;
    for (; i + 4 <= m; i += 4) {
        ushort4 ss = *(const ushort4*)&bk[i];
        unsigned int v0 = h32[(size_t)ss.x * 64 + lane];
        unsigned int v1 = h32[(size_t)ss.y * 64 + lane];
        unsigned int v2 = h32[(size_t)ss.z * 64 + lane];
        unsigned int v3 = h32[(size_t)ss.w * 64 + lane];
        ax += bf2f(v0 & 0xffffu) + bf2f(v1 & 0xffffu) + bf2f(v2 & 0xffffu) + bf2f(v3 & 0xffffu);
        ay += bf2f(v0 >> 16)     + bf2f(v1 >> 16)     + bf2f(v2 >> 16)     + bf2f(v3 >> 16);
    }
    for (; i < m; ++i) {
        unsigned int v = h32[(size_t)bk[i] * 64 + lane];
        ax += bf2f(v & 0xffffu);
        ay += bf2f(v >> 16);
    }

    if (deg > CAP) {                 // exact fallback; few nodes on this data
        int no = *ovfn; if (no > OVF_CAP) no = OVF_CAP;
        for (int o = 0; o < no; ++o) {
            long long pk = ovf[o];
            if ((int)(pk >> 32) == node) {
                unsigned int v = h32[(size_t)(unsigned int)pk * 64 + lane];
                ax += bf2f(v & 0xffffu);
                ay += bf2f(v >> 16);
            }
        }
    }

    float sc = deg > 0 ? 1.0f / (float)deg : 0.f;

    // write in A-frag order
    int rt = node >> 4, mm = node & 15;
    int kc = lane >> 4, q = (lane >> 2) & 3, j = (lane & 3) * 2;
    unsigned int pk = pack2(ax * sc, ay * sc);
    *(unsigned int*)&hagg[(size_t)rt * 2048 + kc * 512 + (q * 16 + mm) * 8 + j] = pk;
}

// ---------------------------------------------------------------------------
// K6: final fused GEMM, no LDS. One wave per 16-row tile.
// out = relu(hbf·Ws^T + b + hagg·We^T). hbf A-frags load as permuted-
// contiguous tiles from row-major; hagg/B frags lane-linear.
// D layout: col = lane&15, row = (lane>>4)*4 + reg.
// ---------------------------------------------------------------------------
__global__ __launch_bounds__(256) void gemm_final(
    const unsigned short* __restrict__ hbf,
    const unsigned short* __restrict__ hagg,
    const unsigned short* __restrict__ Be,
    const unsigned short* __restrict__ Bsf,
    const float* __restrict__ bias,
    float* __restrict__ out,
    int n, int nrt)
{
    int w = (int)((blockIdx.x * blockDim.x + threadIdx.x) >> 6);
    if (w >= nrt) return;
    int l = threadIdx.x & 63;
    int m = l & 15, q = l >> 4;
    int row0 = w * 16;

    bf16x8 ah[4];
#pragma unroll
    for (int kc = 0; kc < 4; ++kc) {
        int gr = row0 + m; if (gr > n - 1) gr = n - 1;
        ah[kc] = *(const bf16x8*)&hbf[(size_t)gr * N_HID + kc * 32 + q * 8];
    }
    const bf16x8* Gp = (const bf16x8*)(hagg + (size_t)w * 2048);
    bf16x8 ag0 = Gp[l], ag1 = Gp[64 + l], ag2 = Gp[128 + l], ag3 = Gp[192 + l];

    const int colb = l & 15;
    const int rq   = (l >> 4) * 4;

#pragma unroll
    for (int ct = 0; ct < 8; ++ct) {
        const bf16x8* BpS = (const bf16x8*)(Bsf + (size_t)ct * 2048);
        const bf16x8* BpE = (const bf16x8*)(Be  + (size_t)ct * 2048);
        f32x4 acc = {0.f, 0.f, 0.f, 0.f};
        acc = __builtin_amdgcn_mfma_f32_16x16x32_bf16(ah[0], BpS[l],       acc, 0, 0, 0);
        acc = __builtin_amdgcn_mfma_f32_16x16x32_bf16(ah[1], BpS[64 + l],  acc, 0, 0, 0);
        acc = __builtin_amdgcn_mfma_f32_16x16x32_bf16(ah[2], BpS[128 + l], acc, 0, 0, 0);
        acc = __builtin_amdgcn_mfma_f32_16x16x32_bf16(ah[3], BpS[192 + l], acc, 0, 0, 0);
        acc = __builtin_amdgcn_mfma_f32_16x16x32_bf16(ag0,   BpE[l],       acc, 0, 0, 0);
        acc = __builtin_amdgcn_mfma_f32_16x16x32_bf16(ag1,   BpE[64 + l],  acc, 0, 0, 0);
        acc = __builtin_amdgcn_mfma_f32_16x16x32_bf16(ag2,   BpE[128 + l], acc, 0, 0, 0);
        acc = __builtin_amdgcn_mfma_f32_16x16x32_bf16(ag3,   BpE[192 + l], acc, 0, 0, 0);

        int col = ct * 16 + colb;
        float bv = bias[col];
#pragma unroll
        for (int r = 0; r < 4; ++r) {
            int row = row0 + rq + r;
            if (row < n) out[(size_t)row * N_HID + col] = fmaxf(acc[r] + bv, 0.f);
        }
    }
}

// ---------------------------------------------------------------------------
extern "C" void kernel_launch(void* const* d_in, const int* in_sizes, int n_in,
                              void* d_out, int out_size, void* d_ws, size_t ws_size,
                              hipStream_t stream)
{
    const float* h   = (const float*)d_in[0];
    const int*   src = (const int*)d_in[1];
    const int*   dst = (const int*)d_in[2];
    const float* We  = (const float*)d_in[3];
    const float* Ws  = (const float*)d_in[4];
    const float* bs  = (const float*)d_in[5];
    float*       out = (float*)d_out;

    const int n   = in_sizes[0] / N_HID;    // 50000
    const int E   = in_sizes[1];            // 800000
    const int nrt = (n + 15) / 16;          // 3125 row tiles
    const float sln = (float)NSLICE / (float)n;
    const int total = n * N_HID;

    // workspace (~33 MB of the 256 MiB d_ws)
    unsigned short* hbf  = (unsigned short*)d_ws;             // n*128 bf16 row-major (12.8 MB)
    unsigned short* hagg = hbf + (size_t)n * N_HID;           // nrt*2048 frag order  (12.8 MB)
    unsigned short* bucket = hagg + (size_t)nrt * 2048;       // n*CAP ushort (3.2 MB)
    unsigned short* Be  = bucket + (size_t)n * CAP;           // 8*2048
    unsigned short* Bs  = Be + 8 * 2048;                      // 8*2048
    int*  cnt  = (int*)(Bs + 8 * 2048);                       // n
    int*  ovfn = cnt + n;                                     // 1 (+pad)
    long long* ovf = (long long*)(ovfn + 8);                  // OVF_CAP
    int*  blockCnt  = (int*)(ovf + OVF_CAP);                  // PBLK*NSLICE
    int*  blockBase = blockCnt + PBLK * NSLICE;               // PBLK*NSLICE
    int*  sbase     = blockBase + PBLK * NSLICE;              // 9 (+pad)
    unsigned int* part = (unsigned int*)(sbase + 16);         // E u32 (3.2 MB)

    const int castBlocks = (total + 2047) / 2048;             // 3125
    const int nodeBlocksPerSlice = ((n / NSLICE) + 4) / 4 + 1;

    count_fragw_cast<<<PBLK + 16 + castBlocks, 256, 0, stream>>>(
        dst, blockCnt, cnt, ovfn, E, n, sln, We, Ws, Be, Bs, h, hbf, total);
    part_scan<<<1, 256, 0, stream>>>(blockCnt, blockBase, sbase, E);
    part_scatter<<<PBLK, 256, 0, stream>>>(src, dst, blockBase, part, E, n, sln);
    bucket_scatter2<<<1024, 256, 0, stream>>>(part, sbase, cnt, bucket, ovfn, ovf);
    gather_mean<<<8 * nodeBlocksPerSlice, 256, 0, stream>>>(cnt, bucket, ovfn, ovf,
                                                            hbf, hagg, n, sln);
    gemm_final<<<(nrt + 3) / 4, 256, 0, stream>>>(hbf, hagg, Be, Bs, bs, out, n, nrt);
}